// Round 18
// baseline (412.433 us; speedup 1.0000x reference)
//
#include <hip/hip_runtime.h>

typedef __attribute__((ext_vector_type(8))) short bf16x8;
typedef __attribute__((ext_vector_type(4))) float f32x4;

#define LPAD 2432
#define LKV  2382
#define NSEQ 2304
#define CDIM 512
#define LPSZ (4 * NSEQ * 8)  // l-partial entries per split (rows*heads)

__device__ __forceinline__ unsigned short f2bf(float f) {
  unsigned int u = __builtin_bit_cast(unsigned int, f);
  u += 0x7fffu + ((u >> 16) & 1u);
  return (unsigned short)(u >> 16);
}
__device__ __forceinline__ float bf2f(unsigned short s) {
  unsigned int u = ((unsigned int)s) << 16;
  return __builtin_bit_cast(float, u);
}
__device__ __forceinline__ f32x4 MFMA(bf16x8 a, bf16x8 b, f32x4 c) {
  return __builtin_amdgcn_mfma_f32_16x16x32_bf16(a, b, c, 0, 0, 0);
}
__device__ __forceinline__ void stage16(const unsigned short* g, unsigned short* l) {
  __builtin_amdgcn_global_load_lds((const __attribute__((address_space(1))) void*)g,
                                   (__attribute__((address_space(3))) void*)l, 16, 0, 0);
}
__device__ __forceinline__ unsigned int cvtpk(float a, float b) {
  unsigned int r;
  asm("v_cvt_pk_bf16_f32 %0, %1, %2" : "=v"(r) : "v"(a), "v"(b));
  return r;
}
// interleaved V^T column position within each 32-chunk
__device__ __forceinline__ int Fj(int j) {
  return (j & ~31) | ((j & 15) << 1) | ((j >> 4) & 1);
}

// ---------------- weight transpose + bf16 convert (LDS tiled, coalesced) ----
__device__ __forceinline__ void tr_tile(const float* __restrict__ in,
                                        unsigned short* __restrict__ out,
                                        int K, int N, int tk, int tn, int t) {
  __shared__ float T[32][33];
  int r = t >> 5, c = t & 31;
#pragma unroll
  for (int p = 0; p < 4; p++) {
    int rr = r + p * 8;
    T[rr][c] = in[(size_t)(tk * 32 + rr) * N + tn * 32 + c];
  }
  __syncthreads();
#pragma unroll
  for (int p = 0; p < 4; p++) {
    int rr = r + p * 8;
    out[(size_t)(tn * 32 + rr) * K + tk * 32 + c] = f2bf(T[c][rr]);
  }
}

__global__ void k_prep(const float* __restrict__ Wq, const float* __restrict__ Wkv,
                       const float* __restrict__ Wctx, const float* __restrict__ Wout,
                       unsigned short* __restrict__ WqT, unsigned short* __restrict__ WkvT,
                       unsigned short* __restrict__ WctxT, unsigned short* __restrict__ WoutT) {
  int bid = blockIdx.x, t = threadIdx.x;
  if (bid < 256) {
    tr_tile(Wq, WqT, 512, 512, bid >> 4, bid & 15, t);
  } else if (bid < 320) {
    int q = bid - 256;
    tr_tile(Wkv, WkvT, 512, 128, q >> 2, q & 3, t);
  } else if (bid < 416) {
    int q = bid - 320;
    tr_tile(Wctx, WctxT, 768, 128, q >> 2, q & 3, t);
  } else {
    int q = bid - 416;
    tr_tile(Wout, WoutT, 512, 512, q >> 4, q & 15, t);
  }
}

// ---------------- LN over C of x (B,C,N) -> xn bf16 (B*N, C) ----------------
__global__ void k_ln1(const float* __restrict__ x, const float* __restrict__ g,
                      unsigned short* __restrict__ xn) {
  int b = blockIdx.y;
  int i0 = blockIdx.x * 32;
  int t = threadIdx.x;
  int ii = t & 31, ci = t >> 5;
  const float* xb = x + (size_t)b * CDIM * NSEQ;
  __shared__ unsigned short Xs[32][514];
  __shared__ float ls[8][32], ls2[8][32];
  __shared__ float lmu[32], lrs[32];
  float s = 0.f, s2 = 0.f;
  for (int c = ci; c < CDIM; c += 8) {
    float v = xb[(size_t)c * NSEQ + i0 + ii];
    Xs[ii][c] = f2bf(v);
    s += v; s2 += v * v;
  }
  ls[ci][ii] = s; ls2[ci][ii] = s2;
  __syncthreads();
  if (t < 32) {
    float a = 0.f, a2 = 0.f;
    for (int q = 0; q < 8; q++) { a += ls[q][t]; a2 += ls2[q][t]; }
    float mu = a * (1.0f / 512.0f);
    float var = a2 * (1.0f / 512.0f) - mu * mu;
    lmu[t] = mu; lrs[t] = rsqrtf(var + 1e-5f);
  }
  __syncthreads();
  int rr = t >> 3, cl0 = (t & 7) * 8;
  float mu = lmu[rr], rs = lrs[rr];
  unsigned short* xrow = xn + (size_t)(b * NSEQ + i0 + rr) * CDIM;
#pragma unroll
  for (int cb = 0; cb < 8; cb++) {
    int c0 = cb * 64 + cl0;
    union { unsigned int w4[4]; uint4 u; } pk;
#pragma unroll
    for (int m = 0; m < 4; m++) {
      float v0 = (bf2f(Xs[rr][c0 + 2 * m]) - mu) * rs * g[c0 + 2 * m];
      float v1 = (bf2f(Xs[rr][c0 + 2 * m + 1]) - mu) * rs * g[c0 + 2 * m + 1];
      pk.w4[m] = cvtpk(v0, v1);
    }
    *reinterpret_cast<uint4*>(xrow + c0) = pk.u;
  }
}

// ---------------- context LN + projection; null row + zero pads ----------
__global__ void k_ctx(const float* __restrict__ ctx, const float* __restrict__ g,
                      const float* __restrict__ be, const unsigned short* __restrict__ WctxT,
                      const float* __restrict__ bctx, const float* __restrict__ null_kv,
                      unsigned short* __restrict__ kb, unsigned short* __restrict__ vt) {
  int b = blockIdx.y, j = blockIdx.x;
  int t = threadIdx.x;
  if (j == 77) {
    if (t < 64) kb[((size_t)b * LPAD + 77) * 64 + t] = f2bf(null_kv[t]);
    else vt[((size_t)b * 64 + (t - 64)) * LPAD + Fj(77)] = f2bf(null_kv[64 + (t - 64)]);
    return;
  }
  if (j > 77) {
    int jj = LKV + (j - 78);
    if (t < 64) kb[((size_t)b * LPAD + jj) * 64 + t] = 0;
    else vt[((size_t)b * 64 + (t - 64)) * LPAD + Fj(jj)] = 0;
    return;
  }
  __shared__ float row[768];
  __shared__ float red[4];
  const float* src = ctx + (size_t)(b * 77 + j) * 768;
  float s = 0.f, s2 = 0.f;
  for (int k = t; k < 768; k += 128) {
    float v = src[k];
    row[k] = v; s += v; s2 += v * v;
  }
  for (int o = 32; o; o >>= 1) { s += __shfl_xor(s, o); s2 += __shfl_xor(s2, o); }
  if ((t & 63) == 0) { red[(t >> 6) * 2] = s; red[(t >> 6) * 2 + 1] = s2; }
  __syncthreads();
  float S = red[0] + red[2], S2 = red[1] + red[3];
  float mu = S * (1.0f / 768.0f);
  float rs = rsqrtf(S2 * (1.0f / 768.0f) - mu * mu + 1e-5f);
  __syncthreads();
  for (int k = t; k < 768; k += 128) row[k] = (row[k] - mu) * rs * g[k] + be[k];
  __syncthreads();
  const uint4* w4 = reinterpret_cast<const uint4*>(WctxT + (size_t)t * 768);
  float acc = 0.f;
  for (int k8 = 0; k8 < 96; k8++) {
    union { uint4 u; unsigned short s[8]; } wv;
    wv.u = w4[k8];
#pragma unroll
    for (int e = 0; e < 8; e++) acc += row[k8 * 8 + e] * bf2f(wv.s[e]);
  }
  acc += bctx[t];
  if (t < 64) kb[((size_t)b * LPAD + j) * 64 + t] = f2bf(acc);
  else vt[((size_t)b * 64 + (t - 64)) * LPAD + Fj(j)] = f2bf(acc);
}

// ---------------- MFMA GEMM: BM=128 BN=64 BK=64, global_load_lds + dbuf -----
template <int MODE>
__global__ __launch_bounds__(256, 1) void k_gemm(
    const unsigned short* __restrict__ A, const unsigned short* __restrict__ BT0,
    const unsigned short* __restrict__ BT1, unsigned short* __restrict__ out_q,
    unsigned short* __restrict__ out_k, unsigned short* __restrict__ out_vt,
    unsigned short* __restrict__ out_proj) {
  int m0 = blockIdx.x * 128, n0 = blockIdx.y * 64;
  int t = threadIdx.x;
  int lane = t & 63, w = t >> 6;
  int wm = w >> 1, wn = w & 1;
  int G = lane >> 4, li = lane & 15, li7 = lane & 7;
  __shared__ __align__(16) unsigned short Al[2][8192];  // 128 x 64
  __shared__ __align__(16) unsigned short Bl[2][4096];  // 64 x 64
  const unsigned short* BT = (MODE == 0 && n0 >= 512) ? BT1 : BT0;
  int bn0 = (MODE == 0 && n0 >= 512) ? n0 - 512 : n0;

  f32x4 zero = {0.f, 0.f, 0.f, 0.f};
  f32x4 acc[4][2];
#pragma unroll
  for (int a = 0; a < 4; a++)
#pragma unroll
    for (int c = 0; c < 2; c++) acc[a][c] = zero;

#define STAGE_AB(buf, k0)                                                              \
  {                                                                                    \
    _Pragma("unroll") for (int p = 0; p < 4; p++) {                                    \
      int gA = p * 256 + t;                                                            \
      int ra = gA >> 3;                                                                \
      int ca = ((gA & 7) ^ (ra & 7)) * 8;                                              \
      stage16(A + (size_t)(m0 + ra) * 512 + (k0) + ca, &Al[buf][(p * 256 + w * 64) * 8]); \
    }                                                                                  \
    _Pragma("unroll") for (int p = 0; p < 2; p++) {                                    \
      int gB = p * 256 + t;                                                            \
      int rb = gB >> 3;                                                                \
      int cb = ((gB & 7) ^ (rb & 7)) * 8;                                              \
      stage16(BT + (size_t)(bn0 + rb) * 512 + (k0) + cb, &Bl[buf][(p * 256 + w * 64) * 8]); \
    }                                                                                  \
  }

  STAGE_AB(0, 0)
  __syncthreads();

  for (int u = 0; u < 8; u++) {
    int cur = u & 1, nxt = cur ^ 1;
    if (u < 7) STAGE_AB(nxt, (u + 1) * 64)
    const char* Ac = (const char*)Al[cur];
    const char* Bc = (const char*)Bl[cur];
#pragma unroll
    for (int ks = 0; ks < 2; ks++) {
      bf16x8 af[4], bfr[2];
#pragma unroll
      for (int f = 0; f < 4; f++)
        af[f] = *reinterpret_cast<const bf16x8*>(
            Ac + ((((wm * 64 + f * 16 + li) * 8) + ((ks * 4 + G) ^ li7)) << 4));
#pragma unroll
      for (int f = 0; f < 2; f++)
        bfr[f] = *reinterpret_cast<const bf16x8*>(
            Bc + ((((wn * 32 + f * 16 + li) * 8) + ((ks * 4 + G) ^ li7)) << 4));
#pragma unroll
      for (int fm = 0; fm < 4; fm++)
#pragma unroll
        for (int fn = 0; fn < 2; fn++)
          acc[fm][fn] = MFMA(af[fm], bfr[fn], acc[fm][fn]);
    }
    __syncthreads();
  }
#undef STAGE_AB

#pragma unroll
  for (int fm = 0; fm < 4; fm++)
#pragma unroll
    for (int fn = 0; fn < 2; fn++)
#pragma unroll
      for (int r = 0; r < 4; r++) {
        int row = m0 + wm * 64 + fm * 16 + G * 4 + r;
        int col = n0 + wn * 32 + fn * 16 + li;
        float v = acc[fm][fn][r];
        if (MODE == 0) {
          int b = row / NSEQ, i = row - b * NSEQ;
          // q pre-scaled by 1/sqrt(dh) * log2(e): softmax runs in exp2 domain
          if (col < 512) out_q[(size_t)row * 512 + col] = f2bf(v * 0.18033688011112042f);
          else if (col < 576) out_k[((size_t)b * LPAD + 78 + i) * 64 + (col - 512)] = f2bf(v);
          else out_vt[((size_t)b * 64 + (col - 576)) * LPAD + Fj(78 + i)] = f2bf(v);
        } else {
          out_proj[(size_t)row * 512 + col] = f2bf(v);
        }
      }
}

// ---------------- flash attention: 4-way KV split, K-only LDS (8KB) ---------
// V is NOT staged: with the Fj-interleaved global V^T layout, each lane's PV
// A-fragment is one contiguous 16B at vt[d][j0 + G*8] (A k-slot (G,e) <-> j =
// j0+(e&1)*16+G*4+(e>>1), and Fj(j)=G*8+e). V (2.4MB) is L2/L3-resident and
// shared by all blocks of a batch. K double-buffered 2x4KB = 8KB LDS ->
// up to 8 blocks/CU if VGPR <= 64 (launch_bounds(256,8); natural demand ~56).
__global__ __launch_bounds__(256, 8) void k_attn(
    const unsigned short* __restrict__ q, const unsigned short* __restrict__ kbuf,
    const unsigned short* __restrict__ vt, unsigned short* __restrict__ pO0,
    unsigned short* __restrict__ pO1, unsigned short* __restrict__ pO2,
    unsigned short* __restrict__ pO3, unsigned short* __restrict__ lp) {
  int bx = blockIdx.x;
  int it = bx >> 2, sp = bx & 3;
  int hh = blockIdx.y, b = blockIdx.z;
  int i0 = it * 32;
  int t = threadIdx.x;
  int w = t >> 6, lane = t & 63;
  int G = lane >> 4, li = lane & 15, li7 = lane & 7;
  int h = hh * 4 + w;

  __shared__ __align__(16) unsigned short Kl[2][2048];  // 32 rows x 64 d (4KB)

  int rk = t >> 3;
  int ck = ((t & 7) ^ (rk & 7)) * 8;

  const unsigned short* kbase = kbuf + (size_t)b * LPAD * 64;
  // per-lane V base: row d = fd*16+li, contiguous 16B chunk G
  const unsigned short* vrow = vt + ((size_t)b * 64 + li) * LPAD + G * 8;

  bf16x8 qf[2][2];
#pragma unroll
  for (int fi = 0; fi < 2; fi++)
#pragma unroll
    for (int ks = 0; ks < 2; ks++)
      qf[fi][ks] = *reinterpret_cast<const bf16x8*>(
          q + (size_t)(b * NSEQ + i0 + fi * 16 + li) * CDIM + h * 64 + ks * 32 + G * 8);

  int jt0 = sp * 19;  // 76 tiles of 32 / 4 splits = 19 exact

  stage16(kbase + (size_t)(jt0 * 32 + rk) * 64 + ck, &Kl[0][w * 512]);

  f32x4 zero = {0.f, 0.f, 0.f, 0.f};
  f32x4 OT[4][2];
#pragma unroll
  for (int fd = 0; fd < 4; fd++)
#pragma unroll
    for (int fi = 0; fi < 2; fi++) OT[fd][fi] = zero;
  float l_[2] = {0.f, 0.f};

  __syncthreads();

  for (int u = 0; u < 19; u++) {
    int jt = jt0 + u;
    int cur = u & 1, nxt = cur ^ 1;
    int j0 = jt * 32;
    if (u + 1 < 19)
      stage16(kbase + (size_t)(j0 + 32 + rk) * 64 + ck, &Kl[nxt][w * 512]);
    const char* Kc = (const char*)Kl[cur];

    f32x4 S[2][2];
#pragma unroll
    for (int fj = 0; fj < 2; fj++) { S[fj][0] = zero; S[fj][1] = zero; }
#pragma unroll
    for (int ks = 0; ks < 2; ks++) {
      bf16x8 kf[2];
#pragma unroll
      for (int fj = 0; fj < 2; fj++)
        kf[fj] = *reinterpret_cast<const bf16x8*>(
            Kc + ((((fj * 16 + li) * 8) + ((ks * 4 + G) ^ li7)) << 4));
#pragma unroll
      for (int fj = 0; fj < 2; fj++)
#pragma unroll
        for (int fi = 0; fi < 2; fi++)
          S[fj][fi] = MFMA(kf[fj], qf[fi][ks], S[fj][fi]);
    }
    if (j0 + 32 > LKV) {
#pragma unroll
      for (int fj = 0; fj < 2; fj++)
#pragma unroll
        for (int r = 0; r < 4; r++) {
          int jg = j0 + fj * 16 + G * 4 + r;
          if (jg >= LKV) { S[fj][0][r] = -1e30f; S[fj][1][r] = -1e30f; }
        }
    }
    bf16x8 pf[2];
#pragma unroll
    for (int fi = 0; fi < 2; fi++) {
      float e[2][4];
#pragma unroll
      for (int fj = 0; fj < 2; fj++)
#pragma unroll
        for (int r = 0; r < 4; r++) e[fj][r] = __builtin_exp2f(S[fj][fi][r]);
      float s0 = (e[0][0] + e[0][1]) + (e[0][2] + e[0][3]);
      float s1 = (e[1][0] + e[1][1]) + (e[1][2] + e[1][3]);
      l_[fi] += s0 + s1;
      union { unsigned int w4[4]; bf16x8 v; } u2;
#pragma unroll
      for (int m = 0; m < 4; m++) u2.w4[m] = cvtpk(e[0][m], e[1][m]);
      pf[fi] = u2.v;
    }
    // PV: V^T fragments straight from global (Fj layout -> contiguous 16B)
#pragma unroll
    for (int fd = 0; fd < 4; fd++) {
      bf16x8 uv = *reinterpret_cast<const bf16x8*>(vrow + (size_t)(fd * 16) * LPAD + j0);
#pragma unroll
      for (int fi = 0; fi < 2; fi++) OT[fd][fi] = MFMA(uv, pf[fi], OT[fd][fi]);
    }
    __syncthreads();
  }

  unsigned short* pO = (sp == 0) ? pO0 : (sp == 1) ? pO1 : (sp == 2) ? pO2 : pO3;
#pragma unroll
  for (int fi = 0; fi < 2; fi++) {
    l_[fi] += __shfl_xor(l_[fi], 16);
    l_[fi] += __shfl_xor(l_[fi], 32);
    int row = b * NSEQ + i0 + fi * 16 + li;
    if (G == 0) lp[sp * LPSZ + row * 8 + h] = f2bf(l_[fi]);
#pragma unroll
    for (int fd = 0; fd < 4; fd++) {
      union { unsigned int w2[2]; uint2 u2; } pk;
      pk.w2[0] = cvtpk(OT[fd][fi][0], OT[fd][fi][1]);
      pk.w2[1] = cvtpk(OT[fd][fi][2], OT[fd][fi][3]);
      *reinterpret_cast<uint2*>(pO + (size_t)row * CDIM + h * 64 + fd * 16 + G * 4) = pk.u2;
    }
  }
}

// ---------------- merge the four KV-split partials ----------------
__global__ void k_merge(unsigned short* __restrict__ pO0,
                        const unsigned short* __restrict__ pO1,
                        const unsigned short* __restrict__ pO2,
                        const unsigned short* __restrict__ pO3,
                        const unsigned short* __restrict__ lp) {
  int c = blockIdx.x * 256 + threadIdx.x;
  size_t base = (size_t)c * 8;
  int row = (int)(base >> 9);
  int h = (int)((base >> 6) & 7);
  int li = row * 8 + h;
  float l = bf2f(lp[li]) + bf2f(lp[LPSZ + li]) + bf2f(lp[2 * LPSZ + li]) + bf2f(lp[3 * LPSZ + li]);
  float inv = 1.0f / l;
  union { uint4 u; unsigned short s[8]; } a0, a1, a2, a3, o;
  a0.u = *reinterpret_cast<const uint4*>(pO0 + base);
  a1.u = *reinterpret_cast<const uint4*>(pO1 + base);
  a2.u = *reinterpret_cast<const uint4*>(pO2 + base);
  a3.u = *reinterpret_cast<const uint4*>(pO3 + base);
  unsigned int* ow = reinterpret_cast<unsigned int*>(&o.u);
#pragma unroll
  for (int m = 0; m < 4; m++) {
    float v0 = (bf2f(a0.s[2 * m]) + bf2f(a1.s[2 * m]) + bf2f(a2.s[2 * m]) + bf2f(a3.s[2 * m])) * inv;
    float v1 = (bf2f(a0.s[2 * m + 1]) + bf2f(a1.s[2 * m + 1]) + bf2f(a2.s[2 * m + 1]) +
                bf2f(a3.s[2 * m + 1])) * inv;
    ow[m] = cvtpk(v0, v1);
  }
  *reinterpret_cast<uint4*>(pO0 + base) = o.u;
}

// ---------------- per-row LN stats of proj (bf16, coalesced) ----------------
__global__ void k_stats(const unsigned short* __restrict__ proj, float* __restrict__ musig) {
  int w = threadIdx.x >> 6, lane = threadIdx.x & 63;
  int row = blockIdx.x * 4 + w;
  union { uint4 u; unsigned short s[8]; } a;
  a.u = *reinterpret_cast<const uint4*>(proj + (size_t)row * CDIM + lane * 8);
  float s = 0.f, s2 = 0.f;
#pragma unroll
  for (int m = 0; m < 8; m++) {
    float v = bf2f(a.s[m]);
    s += v; s2 += v * v;
  }
  for (int o = 32; o; o >>= 1) { s += __shfl_xor(s, o); s2 += __shfl_xor(s2, o); }
  if (lane == 0) {
    float mu = s * (1.0f / 512.0f);
    float var = s2 * (1.0f / 512.0f) - mu * mu;
    musig[row] = mu;
    musig[4 * NSEQ + row] = rsqrtf(var + 1e-5f);
  }
}

// ---------------- final LN + residual, LDS-transposed, fully coalesced ------
__global__ void k_final2(const unsigned short* __restrict__ proj, const float* __restrict__ musig,
                         const float* __restrict__ g, const float* __restrict__ x,
                         float* __restrict__ y) {
  int i0 = blockIdx.x * 32, c0 = blockIdx.y * 64, b = blockIdx.z;
  int t = threadIdx.x;
  __shared__ float lds[32][65];
  {
    int il = t >> 3, cB = (t & 7) * 8;
    union { uint4 u; unsigned short s[8]; } a;
    a.u = *reinterpret_cast<const uint4*>(proj + (size_t)(b * NSEQ + i0 + il) * CDIM + c0 + cB);
#pragma unroll
    for (int m = 0; m < 8; m++) lds[il][cB + m] = bf2f(a.s[m]);
  }
  __syncthreads();
  int ii = t & 31, cg = t >> 5;
  float mu = musig[b * NSEQ + i0 + ii];
  float rs = musig[4 * NSEQ + b * NSEQ + i0 + ii];
  const float* xb = x + (size_t)b * CDIM * NSEQ;
  float* yb = y + (size_t)b * CDIM * NSEQ;
#pragma unroll
  for (int cc = 0; cc < 8; cc++) {
    int cl = cg * 8 + cc;
    int c = c0 + cl;
    float v = lds[ii][cl];
    yb[(size_t)c * NSEQ + i0 + ii] = xb[(size_t)c * NSEQ + i0 + ii] + (v - mu) * rs * g[c];
  }
}

extern "C" void kernel_launch(void* const* d_in, const int* in_sizes, int n_in,
                              void* d_out, int out_size, void* d_ws, size_t ws_size,
                              hipStream_t stream) {
  const float* x       = (const float*)d_in[0];
  const float* context = (const float*)d_in[1];
  const float* ngamma  = (const float*)d_in[2];
  const float* null_kv = (const float*)d_in[3];
  const float* Wq      = (const float*)d_in[4];
  const float* Wkv     = (const float*)d_in[5];
  const float* clng    = (const float*)d_in[6];
  const float* clnb    = (const float*)d_in[7];
  const float* Wctx    = (const float*)d_in[8];
  const float* bctx    = (const float*)d_in[9];
  const float* Wout    = (const float*)d_in[10];
  const float* olng    = (const float*)d_in[11];
  float* y = (float*)d_out;
  char* ws = (char*)d_ws;

  unsigned short* xn    = (unsigned short*)(ws);              // 9437184 B (pO1 during attn)
  unsigned short* qb    = (unsigned short*)(ws + 9437184);    // 9437184 B
  unsigned short* proj  = (unsigned short*)(ws);              // bf16, aliases xn (dead by then)
  unsigned short* aoutb = (unsigned short*)(ws + 18874368);   // 9437184 B (pO0 -> merged)
  float* musig          = (float*)(ws + 18874368);            // aliases aoutb (dead after gemm1)
  unsigned short* kb    = (unsigned short*)(ws + 28311552);   // 1245184 B
  unsigned short* vtb   = (unsigned short*)(ws + 29556736);   // 1245184 B
  unsigned short* WqT   = (unsigned short*)(ws + 30801920);   // 524288 B
  unsigned short* WkvT  = (unsigned short*)(ws + 31326208);   // 131072 B
  unsigned short* WctxT = (unsigned short*)(ws + 31457280);   // 196608 B
  unsigned short* WoutT = (unsigned short*)(ws + 31653888);   // 524288 B
  // bf16 l-partials: 4 x 73728 x 2B = 589824 B, overlay WqT+WkvT (dead after gemm0)
  unsigned short* lpart = (unsigned short*)(ws + 30801920);
  // partials 2,3 live in d_out (18874368 B); k_final2 fully rewrites y after.
  unsigned short* pO2   = (unsigned short*)d_out;
  unsigned short* pO3   = (unsigned short*)d_out + 4718592;

  k_prep<<<dim3(672), dim3(256), 0, stream>>>(Wq, Wkv, Wctx, Wout, WqT, WkvT, WctxT, WoutT);
  k_ln1<<<dim3(72, 4), dim3(256), 0, stream>>>(x, ngamma, xn);
  k_ctx<<<dim3(128, 4), dim3(128), 0, stream>>>(context, clng, clnb, WctxT, bctx, null_kv, kb, vtb);
  k_gemm<0><<<dim3(72, 10), dim3(256), 0, stream>>>(xn, WqT, WkvT, qb, kb, vtb, nullptr);
  k_attn<<<dim3(288, 2, 4), dim3(256), 0, stream>>>(qb, kb, vtb, aoutb, xn, pO2, pO3, lpart);
  k_merge<<<dim3(2304), dim3(256), 0, stream>>>(aoutb, xn, pO2, pO3, lpart);
  k_gemm<1><<<dim3(72, 8), dim3(256), 0, stream>>>(aoutb, WoutT, nullptr, nullptr, nullptr, nullptr, proj);
  k_stats<<<dim3(2304), dim3(256), 0, stream>>>(proj, musig);
  k_final2<<<dim3(72, 8, 4), dim3(256), 0, stream>>>(proj, musig, olng, x, y);
}

// Round 19
// 200.499 us; speedup vs baseline: 2.0570x; 2.0570x over previous
//
#include <hip/hip_runtime.h>

typedef __attribute__((ext_vector_type(8))) short bf16x8;
typedef __attribute__((ext_vector_type(4))) float f32x4;

#define LPAD 2432
#define LKV  2382
#define NSEQ 2304
#define CDIM 512
#define LPSZ (4 * NSEQ * 8)  // l-partial entries per split (rows*heads)

__device__ __forceinline__ unsigned short f2bf(float f) {
  unsigned int u = __builtin_bit_cast(unsigned int, f);
  u += 0x7fffu + ((u >> 16) & 1u);
  return (unsigned short)(u >> 16);
}
__device__ __forceinline__ float bf2f(unsigned short s) {
  unsigned int u = ((unsigned int)s) << 16;
  return __builtin_bit_cast(float, u);
}
__device__ __forceinline__ f32x4 MFMA(bf16x8 a, bf16x8 b, f32x4 c) {
  return __builtin_amdgcn_mfma_f32_16x16x32_bf16(a, b, c, 0, 0, 0);
}
__device__ __forceinline__ void stage16(const unsigned short* g, unsigned short* l) {
  __builtin_amdgcn_global_load_lds((const __attribute__((address_space(1))) void*)g,
                                   (__attribute__((address_space(3))) void*)l, 16, 0, 0);
}
__device__ __forceinline__ unsigned int cvtpk(float a, float b) {
  unsigned int r;
  asm("v_cvt_pk_bf16_f32 %0, %1, %2" : "=v"(r) : "v"(a), "v"(b));
  return r;
}
// interleaved V^T column position within each 32-chunk
__device__ __forceinline__ int Fj(int j) {
  return (j & ~31) | ((j & 15) << 1) | ((j >> 4) & 1);
}

// ---------------- weight transpose + bf16 convert (LDS tiled, coalesced) ----
__device__ __forceinline__ void tr_tile(const float* __restrict__ in,
                                        unsigned short* __restrict__ out,
                                        int K, int N, int tk, int tn, int t) {
  __shared__ float T[32][33];
  int r = t >> 5, c = t & 31;
#pragma unroll
  for (int p = 0; p < 4; p++) {
    int rr = r + p * 8;
    T[rr][c] = in[(size_t)(tk * 32 + rr) * N + tn * 32 + c];
  }
  __syncthreads();
#pragma unroll
  for (int p = 0; p < 4; p++) {
    int rr = r + p * 8;
    out[(size_t)(tn * 32 + rr) * K + tk * 32 + c] = f2bf(T[c][rr]);
  }
}

__global__ void k_prep(const float* __restrict__ Wq, const float* __restrict__ Wkv,
                       const float* __restrict__ Wctx, const float* __restrict__ Wout,
                       unsigned short* __restrict__ WqT, unsigned short* __restrict__ WkvT,
                       unsigned short* __restrict__ WctxT, unsigned short* __restrict__ WoutT) {
  int bid = blockIdx.x, t = threadIdx.x;
  if (bid < 256) {
    tr_tile(Wq, WqT, 512, 512, bid >> 4, bid & 15, t);
  } else if (bid < 320) {
    int q = bid - 256;
    tr_tile(Wkv, WkvT, 512, 128, q >> 2, q & 3, t);
  } else if (bid < 416) {
    int q = bid - 320;
    tr_tile(Wctx, WctxT, 768, 128, q >> 2, q & 3, t);
  } else {
    int q = bid - 416;
    tr_tile(Wout, WoutT, 512, 512, q >> 4, q & 15, t);
  }
}

// ---------------- LN over C of x (B,C,N) -> xn bf16 (B*N, C) ----------------
__global__ void k_ln1(const float* __restrict__ x, const float* __restrict__ g,
                      unsigned short* __restrict__ xn) {
  int b = blockIdx.y;
  int i0 = blockIdx.x * 32;
  int t = threadIdx.x;
  int ii = t & 31, ci = t >> 5;
  const float* xb = x + (size_t)b * CDIM * NSEQ;
  __shared__ unsigned short Xs[32][514];
  __shared__ float ls[8][32], ls2[8][32];
  __shared__ float lmu[32], lrs[32];
  float s = 0.f, s2 = 0.f;
  for (int c = ci; c < CDIM; c += 8) {
    float v = xb[(size_t)c * NSEQ + i0 + ii];
    Xs[ii][c] = f2bf(v);
    s += v; s2 += v * v;
  }
  ls[ci][ii] = s; ls2[ci][ii] = s2;
  __syncthreads();
  if (t < 32) {
    float a = 0.f, a2 = 0.f;
    for (int q = 0; q < 8; q++) { a += ls[q][t]; a2 += ls2[q][t]; }
    float mu = a * (1.0f / 512.0f);
    float var = a2 * (1.0f / 512.0f) - mu * mu;
    lmu[t] = mu; lrs[t] = rsqrtf(var + 1e-5f);
  }
  __syncthreads();
  int rr = t >> 3, cl0 = (t & 7) * 8;
  float mu = lmu[rr], rs = lrs[rr];
  unsigned short* xrow = xn + (size_t)(b * NSEQ + i0 + rr) * CDIM;
#pragma unroll
  for (int cb = 0; cb < 8; cb++) {
    int c0 = cb * 64 + cl0;
    union { unsigned int w4[4]; uint4 u; } pk;
#pragma unroll
    for (int m = 0; m < 4; m++) {
      float v0 = (bf2f(Xs[rr][c0 + 2 * m]) - mu) * rs * g[c0 + 2 * m];
      float v1 = (bf2f(Xs[rr][c0 + 2 * m + 1]) - mu) * rs * g[c0 + 2 * m + 1];
      pk.w4[m] = cvtpk(v0, v1);
    }
    *reinterpret_cast<uint4*>(xrow + c0) = pk.u;
  }
}

// ---------------- context LN + projection; null row + zero pads ----------
__global__ void k_ctx(const float* __restrict__ ctx, const float* __restrict__ g,
                      const float* __restrict__ be, const unsigned short* __restrict__ WctxT,
                      const float* __restrict__ bctx, const float* __restrict__ null_kv,
                      unsigned short* __restrict__ kb, unsigned short* __restrict__ vt) {
  int b = blockIdx.y, j = blockIdx.x;
  int t = threadIdx.x;
  if (j == 77) {
    if (t < 64) kb[((size_t)b * LPAD + 77) * 64 + t] = f2bf(null_kv[t]);
    else vt[((size_t)b * 64 + (t - 64)) * LPAD + Fj(77)] = f2bf(null_kv[64 + (t - 64)]);
    return;
  }
  if (j > 77) {
    int jj = LKV + (j - 78);
    if (t < 64) kb[((size_t)b * LPAD + jj) * 64 + t] = 0;
    else vt[((size_t)b * 64 + (t - 64)) * LPAD + Fj(jj)] = 0;
    return;
  }
  __shared__ float row[768];
  __shared__ float red[4];
  const float* src = ctx + (size_t)(b * 77 + j) * 768;
  float s = 0.f, s2 = 0.f;
  for (int k = t; k < 768; k += 128) {
    float v = src[k];
    row[k] = v; s += v; s2 += v * v;
  }
  for (int o = 32; o; o >>= 1) { s += __shfl_xor(s, o); s2 += __shfl_xor(s2, o); }
  if ((t & 63) == 0) { red[(t >> 6) * 2] = s; red[(t >> 6) * 2 + 1] = s2; }
  __syncthreads();
  float S = red[0] + red[2], S2 = red[1] + red[3];
  float mu = S * (1.0f / 768.0f);
  float rs = rsqrtf(S2 * (1.0f / 768.0f) - mu * mu + 1e-5f);
  __syncthreads();
  for (int k = t; k < 768; k += 128) row[k] = (row[k] - mu) * rs * g[k] + be[k];
  __syncthreads();
  const uint4* w4 = reinterpret_cast<const uint4*>(WctxT + (size_t)t * 768);
  float acc = 0.f;
  for (int k8 = 0; k8 < 96; k8++) {
    union { uint4 u; unsigned short s[8]; } wv;
    wv.u = w4[k8];
#pragma unroll
    for (int e = 0; e < 8; e++) acc += row[k8 * 8 + e] * bf2f(wv.s[e]);
  }
  acc += bctx[t];
  if (t < 64) kb[((size_t)b * LPAD + j) * 64 + t] = f2bf(acc);
  else vt[((size_t)b * 64 + (t - 64)) * LPAD + Fj(j)] = f2bf(acc);
}

// ---------------- MFMA GEMM: BM=128 BN=64 BK=64, global_load_lds + dbuf -----
template <int MODE>
__global__ __launch_bounds__(256, 1) void k_gemm(
    const unsigned short* __restrict__ A, const unsigned short* __restrict__ BT0,
    const unsigned short* __restrict__ BT1, unsigned short* __restrict__ out_q,
    unsigned short* __restrict__ out_k, unsigned short* __restrict__ out_vt,
    unsigned short* __restrict__ out_proj) {
  int m0 = blockIdx.x * 128, n0 = blockIdx.y * 64;
  int t = threadIdx.x;
  int lane = t & 63, w = t >> 6;
  int wm = w >> 1, wn = w & 1;
  int G = lane >> 4, li = lane & 15, li7 = lane & 7;
  __shared__ __align__(16) unsigned short Al[2][8192];  // 128 x 64
  __shared__ __align__(16) unsigned short Bl[2][4096];  // 64 x 64
  const unsigned short* BT = (MODE == 0 && n0 >= 512) ? BT1 : BT0;
  int bn0 = (MODE == 0 && n0 >= 512) ? n0 - 512 : n0;

  f32x4 zero = {0.f, 0.f, 0.f, 0.f};
  f32x4 acc[4][2];
#pragma unroll
  for (int a = 0; a < 4; a++)
#pragma unroll
    for (int c = 0; c < 2; c++) acc[a][c] = zero;

#define STAGE_AB(buf, k0)                                                              \
  {                                                                                    \
    _Pragma("unroll") for (int p = 0; p < 4; p++) {                                    \
      int gA = p * 256 + t;                                                            \
      int ra = gA >> 3;                                                                \
      int ca = ((gA & 7) ^ (ra & 7)) * 8;                                              \
      stage16(A + (size_t)(m0 + ra) * 512 + (k0) + ca, &Al[buf][(p * 256 + w * 64) * 8]); \
    }                                                                                  \
    _Pragma("unroll") for (int p = 0; p < 2; p++) {                                    \
      int gB = p * 256 + t;                                                            \
      int rb = gB >> 3;                                                                \
      int cb = ((gB & 7) ^ (rb & 7)) * 8;                                              \
      stage16(BT + (size_t)(bn0 + rb) * 512 + (k0) + cb, &Bl[buf][(p * 256 + w * 64) * 8]); \
    }                                                                                  \
  }

  STAGE_AB(0, 0)
  __syncthreads();

  for (int u = 0; u < 8; u++) {
    int cur = u & 1, nxt = cur ^ 1;
    if (u < 7) STAGE_AB(nxt, (u + 1) * 64)
    const char* Ac = (const char*)Al[cur];
    const char* Bc = (const char*)Bl[cur];
#pragma unroll
    for (int ks = 0; ks < 2; ks++) {
      bf16x8 af[4], bfr[2];
#pragma unroll
      for (int f = 0; f < 4; f++)
        af[f] = *reinterpret_cast<const bf16x8*>(
            Ac + ((((wm * 64 + f * 16 + li) * 8) + ((ks * 4 + G) ^ li7)) << 4));
#pragma unroll
      for (int f = 0; f < 2; f++)
        bfr[f] = *reinterpret_cast<const bf16x8*>(
            Bc + ((((wn * 32 + f * 16 + li) * 8) + ((ks * 4 + G) ^ li7)) << 4));
#pragma unroll
      for (int fm = 0; fm < 4; fm++)
#pragma unroll
        for (int fn = 0; fn < 2; fn++)
          acc[fm][fn] = MFMA(af[fm], bfr[fn], acc[fm][fn]);
    }
    __syncthreads();
  }
#undef STAGE_AB

#pragma unroll
  for (int fm = 0; fm < 4; fm++)
#pragma unroll
    for (int fn = 0; fn < 2; fn++)
#pragma unroll
      for (int r = 0; r < 4; r++) {
        int row = m0 + wm * 64 + fm * 16 + G * 4 + r;
        int col = n0 + wn * 32 + fn * 16 + li;
        float v = acc[fm][fn][r];
        if (MODE == 0) {
          int b = row / NSEQ, i = row - b * NSEQ;
          // q pre-scaled by 1/sqrt(dh) * log2(e): softmax runs in exp2 domain
          if (col < 512) out_q[(size_t)row * 512 + col] = f2bf(v * 0.18033688011112042f);
          else if (col < 576) out_k[((size_t)b * LPAD + 78 + i) * 64 + (col - 512)] = f2bf(v);
          else out_vt[((size_t)b * 64 + (col - 576)) * LPAD + Fj(78 + i)] = f2bf(v);
        } else {
          out_proj[(size_t)row * 512 + col] = f2bf(v);
        }
      }
}

// ---------------- flash attention: 4-way KV split, K-only LDS (8KB) ---------
// V NOT staged (Fj-interleaved global V^T -> each lane's PV A-fragment is one
// contiguous 16B; V is L2-resident, shared by all blocks of a batch).
// launch_bounds(256,4): allocator cap 128 regs (natural ~56, NO spill);
// actual residency set by real usage -> 8KB LDS + 56 VGPR allows up to
// 8 blocks/CU. (R18 lesson: (256,8) forced VGPR=32 -> 690MB spill.)
__global__ __launch_bounds__(256, 4) void k_attn(
    const unsigned short* __restrict__ q, const unsigned short* __restrict__ kbuf,
    const unsigned short* __restrict__ vt, unsigned short* __restrict__ pO0,
    unsigned short* __restrict__ pO1, unsigned short* __restrict__ pO2,
    unsigned short* __restrict__ pO3, unsigned short* __restrict__ lp) {
  int bx = blockIdx.x;
  int it = bx >> 2, sp = bx & 3;
  int hh = blockIdx.y, b = blockIdx.z;
  int i0 = it * 32;
  int t = threadIdx.x;
  int w = t >> 6, lane = t & 63;
  int G = lane >> 4, li = lane & 15, li7 = lane & 7;
  int h = hh * 4 + w;

  __shared__ __align__(16) unsigned short Kl[2][2048];  // 32 rows x 64 d (4KB)

  int rk = t >> 3;
  int ck = ((t & 7) ^ (rk & 7)) * 8;

  const unsigned short* kbase = kbuf + (size_t)b * LPAD * 64;
  // per-lane V base: row d = fd*16+li, contiguous 16B chunk G
  const unsigned short* vrow = vt + ((size_t)b * 64 + li) * LPAD + G * 8;

  bf16x8 qf[2][2];
#pragma unroll
  for (int fi = 0; fi < 2; fi++)
#pragma unroll
    for (int ks = 0; ks < 2; ks++)
      qf[fi][ks] = *reinterpret_cast<const bf16x8*>(
          q + (size_t)(b * NSEQ + i0 + fi * 16 + li) * CDIM + h * 64 + ks * 32 + G * 8);

  int jt0 = sp * 19;  // 76 tiles of 32 / 4 splits = 19 exact

  stage16(kbase + (size_t)(jt0 * 32 + rk) * 64 + ck, &Kl[0][w * 512]);

  f32x4 zero = {0.f, 0.f, 0.f, 0.f};
  f32x4 OT[4][2];
#pragma unroll
  for (int fd = 0; fd < 4; fd++)
#pragma unroll
    for (int fi = 0; fi < 2; fi++) OT[fd][fi] = zero;
  float l_[2] = {0.f, 0.f};

  __syncthreads();

  for (int u = 0; u < 19; u++) {
    int jt = jt0 + u;
    int cur = u & 1, nxt = cur ^ 1;
    int j0 = jt * 32;
    if (u + 1 < 19)
      stage16(kbase + (size_t)(j0 + 32 + rk) * 64 + ck, &Kl[nxt][w * 512]);
    const char* Kc = (const char*)Kl[cur];

    f32x4 S[2][2];
#pragma unroll
    for (int fj = 0; fj < 2; fj++) { S[fj][0] = zero; S[fj][1] = zero; }
#pragma unroll
    for (int ks = 0; ks < 2; ks++) {
      bf16x8 kf[2];
#pragma unroll
      for (int fj = 0; fj < 2; fj++)
        kf[fj] = *reinterpret_cast<const bf16x8*>(
            Kc + ((((fj * 16 + li) * 8) + ((ks * 4 + G) ^ li7)) << 4));
#pragma unroll
      for (int fj = 0; fj < 2; fj++)
#pragma unroll
        for (int fi = 0; fi < 2; fi++)
          S[fj][fi] = MFMA(kf[fj], qf[fi][ks], S[fj][fi]);
    }
    if (j0 + 32 > LKV) {
#pragma unroll
      for (int fj = 0; fj < 2; fj++)
#pragma unroll
        for (int r = 0; r < 4; r++) {
          int jg = j0 + fj * 16 + G * 4 + r;
          if (jg >= LKV) { S[fj][0][r] = -1e30f; S[fj][1][r] = -1e30f; }
        }
    }
    bf16x8 pf[2];
#pragma unroll
    for (int fi = 0; fi < 2; fi++) {
      float e[2][4];
#pragma unroll
      for (int fj = 0; fj < 2; fj++)
#pragma unroll
        for (int r = 0; r < 4; r++) e[fj][r] = __builtin_exp2f(S[fj][fi][r]);
      float s0 = (e[0][0] + e[0][1]) + (e[0][2] + e[0][3]);
      float s1 = (e[1][0] + e[1][1]) + (e[1][2] + e[1][3]);
      l_[fi] += s0 + s1;
      union { unsigned int w4[4]; bf16x8 v; } u2;
#pragma unroll
      for (int m = 0; m < 4; m++) u2.w4[m] = cvtpk(e[0][m], e[1][m]);
      pf[fi] = u2.v;
    }
    // PV: V^T fragments straight from global (Fj layout -> contiguous 16B)
#pragma unroll
    for (int fd = 0; fd < 4; fd++) {
      bf16x8 uv = *reinterpret_cast<const bf16x8*>(vrow + (size_t)(fd * 16) * LPAD + j0);
#pragma unroll
      for (int fi = 0; fi < 2; fi++) OT[fd][fi] = MFMA(uv, pf[fi], OT[fd][fi]);
    }
    __syncthreads();
  }

  unsigned short* pO = (sp == 0) ? pO0 : (sp == 1) ? pO1 : (sp == 2) ? pO2 : pO3;
#pragma unroll
  for (int fi = 0; fi < 2; fi++) {
    l_[fi] += __shfl_xor(l_[fi], 16);
    l_[fi] += __shfl_xor(l_[fi], 32);
    int row = b * NSEQ + i0 + fi * 16 + li;
    if (G == 0) lp[sp * LPSZ + row * 8 + h] = f2bf(l_[fi]);
#pragma unroll
    for (int fd = 0; fd < 4; fd++) {
      union { unsigned int w2[2]; uint2 u2; } pk;
      pk.w2[0] = cvtpk(OT[fd][fi][0], OT[fd][fi][1]);
      pk.w2[1] = cvtpk(OT[fd][fi][2], OT[fd][fi][3]);
      *reinterpret_cast<uint2*>(pO + (size_t)row * CDIM + h * 64 + fd * 16 + G * 4) = pk.u2;
    }
  }
}

// ---------------- merge the four KV-split partials ----------------
__global__ void k_merge(unsigned short* __restrict__ pO0,
                        const unsigned short* __restrict__ pO1,
                        const unsigned short* __restrict__ pO2,
                        const unsigned short* __restrict__ pO3,
                        const unsigned short* __restrict__ lp) {
  int c = blockIdx.x * 256 + threadIdx.x;
  size_t base = (size_t)c * 8;
  int row = (int)(base >> 9);
  int h = (int)((base >> 6) & 7);
  int li = row * 8 + h;
  float l = bf2f(lp[li]) + bf2f(lp[LPSZ + li]) + bf2f(lp[2 * LPSZ + li]) + bf2f(lp[3 * LPSZ + li]);
  float inv = 1.0f / l;
  union { uint4 u; unsigned short s[8]; } a0, a1, a2, a3, o;
  a0.u = *reinterpret_cast<const uint4*>(pO0 + base);
  a1.u = *reinterpret_cast<const uint4*>(pO1 + base);
  a2.u = *reinterpret_cast<const uint4*>(pO2 + base);
  a3.u = *reinterpret_cast<const uint4*>(pO3 + base);
  unsigned int* ow = reinterpret_cast<unsigned int*>(&o.u);
#pragma unroll
  for (int m = 0; m < 4; m++) {
    float v0 = (bf2f(a0.s[2 * m]) + bf2f(a1.s[2 * m]) + bf2f(a2.s[2 * m]) + bf2f(a3.s[2 * m])) * inv;
    float v1 = (bf2f(a0.s[2 * m + 1]) + bf2f(a1.s[2 * m + 1]) + bf2f(a2.s[2 * m + 1]) +
                bf2f(a3.s[2 * m + 1])) * inv;
    ow[m] = cvtpk(v0, v1);
  }
  *reinterpret_cast<uint4*>(pO0 + base) = o.u;
}

// ---------------- per-row LN stats of proj (bf16, coalesced) ----------------
__global__ void k_stats(const unsigned short* __restrict__ proj, float* __restrict__ musig) {
  int w = threadIdx.x >> 6, lane = threadIdx.x & 63;
  int row = blockIdx.x * 4 + w;
  union { uint4 u; unsigned short s[8]; } a;
  a.u = *reinterpret_cast<const uint4*>(proj + (size_t)row * CDIM + lane * 8);
  float s = 0.f, s2 = 0.f;
#pragma unroll
  for (int m = 0; m < 8; m++) {
    float v = bf2f(a.s[m]);
    s += v; s2 += v * v;
  }
  for (int o = 32; o; o >>= 1) { s += __shfl_xor(s, o); s2 += __shfl_xor(s2, o); }
  if (lane == 0) {
    float mu = s * (1.0f / 512.0f);
    float var = s2 * (1.0f / 512.0f) - mu * mu;
    musig[row] = mu;
    musig[4 * NSEQ + row] = rsqrtf(var + 1e-5f);
  }
}

// ---------------- final LN + residual, LDS-transposed, fully coalesced ------
__global__ void k_final2(const unsigned short* __restrict__ proj, const float* __restrict__ musig,
                         const float* __restrict__ g, const float* __restrict__ x,
                         float* __restrict__ y) {
  int i0 = blockIdx.x * 32, c0 = blockIdx.y * 64, b = blockIdx.z;
  int t = threadIdx.x;
  __shared__ float lds[32][65];
  {
    int il = t >> 3, cB = (t & 7) * 8;
    union { uint4 u; unsigned short s[8]; } a;
    a.u = *reinterpret_cast<const uint4*>(proj + (size_t)(b * NSEQ + i0 + il) * CDIM + c0 + cB);
#pragma unroll
    for (int m = 0; m < 8; m++) lds[il][cB + m] = bf2f(a.s[m]);
  }
  __syncthreads();
  int ii = t & 31, cg = t >> 5;
  float mu = musig[b * NSEQ + i0 + ii];
  float rs = musig[4 * NSEQ + b * NSEQ + i0 + ii];
  const float* xb = x + (size_t)b * CDIM * NSEQ;
  float* yb = y + (size_t)b * CDIM * NSEQ;
#pragma unroll
  for (int cc = 0; cc < 8; cc++) {
    int cl = cg * 8 + cc;
    int c = c0 + cl;
    float v = lds[ii][cl];
    yb[(size_t)c * NSEQ + i0 + ii] = xb[(size_t)c * NSEQ + i0 + ii] + (v - mu) * rs * g[c];
  }
}

extern "C" void kernel_launch(void* const* d_in, const int* in_sizes, int n_in,
                              void* d_out, int out_size, void* d_ws, size_t ws_size,
                              hipStream_t stream) {
  const float* x       = (const float*)d_in[0];
  const float* context = (const float*)d_in[1];
  const float* ngamma  = (const float*)d_in[2];
  const float* null_kv = (const float*)d_in[3];
  const float* Wq      = (const float*)d_in[4];
  const float* Wkv     = (const float*)d_in[5];
  const float* clng    = (const float*)d_in[6];
  const float* clnb    = (const float*)d_in[7];
  const float* Wctx    = (const float*)d_in[8];
  const float* bctx    = (const float*)d_in[9];
  const float* Wout    = (const float*)d_in[10];
  const float* olng    = (const float*)d_in[11];
  float* y = (float*)d_out;
  char* ws = (char*)d_ws;

  unsigned short* xn    = (unsigned short*)(ws);              // 9437184 B (pO1 during attn)
  unsigned short* qb    = (unsigned short*)(ws + 9437184);    // 9437184 B
  unsigned short* proj  = (unsigned short*)(ws);              // bf16, aliases xn (dead by then)
  unsigned short* aoutb = (unsigned short*)(ws + 18874368);   // 9437184 B (pO0 -> merged)
  float* musig          = (float*)(ws + 18874368);            // aliases aoutb (dead after gemm1)
  unsigned short* kb    = (unsigned short*)(ws + 28311552);   // 1245184 B
  unsigned short* vtb   = (unsigned short*)(ws + 29556736);   // 1245184 B
  unsigned short* WqT   = (unsigned short*)(ws + 30801920);   // 524288 B
  unsigned short* WkvT  = (unsigned short*)(ws + 31326208);   // 131072 B
  unsigned short* WctxT = (unsigned short*)(ws + 31457280);   // 196608 B
  unsigned short* WoutT = (unsigned short*)(ws + 31653888);   // 524288 B
  // bf16 l-partials: 4 x 73728 x 2B = 589824 B, overlay WqT+WkvT (dead after gemm0)
  unsigned short* lpart = (unsigned short*)(ws + 30801920);
  // partials 2,3 live in d_out (18874368 B); k_final2 fully rewrites y after.
  unsigned short* pO2   = (unsigned short*)d_out;
  unsigned short* pO3   = (unsigned short*)d_out + 4718592;

  k_prep<<<dim3(672), dim3(256), 0, stream>>>(Wq, Wkv, Wctx, Wout, WqT, WkvT, WctxT, WoutT);
  k_ln1<<<dim3(72, 4), dim3(256), 0, stream>>>(x, ngamma, xn);
  k_ctx<<<dim3(128, 4), dim3(128), 0, stream>>>(context, clng, clnb, WctxT, bctx, null_kv, kb, vtb);
  k_gemm<0><<<dim3(72, 10), dim3(256), 0, stream>>>(xn, WqT, WkvT, qb, kb, vtb, nullptr);
  k_attn<<<dim3(288, 2, 4), dim3(256), 0, stream>>>(qb, kb, vtb, aoutb, xn, pO2, pO3, lpart);
  k_merge<<<dim3(2304), dim3(256), 0, stream>>>(aoutb, xn, pO2, pO3, lpart);
  k_gemm<1><<<dim3(72, 8), dim3(256), 0, stream>>>(aoutb, WoutT, nullptr, nullptr, nullptr, nullptr, proj);
  k_stats<<<dim3(2304), dim3(256), 0, stream>>>(proj, musig);
  k_final2<<<dim3(72, 8, 4), dim3(256), 0, stream>>>(proj, musig, olng, x, y);
}

// Round 20
// 167.692 us; speedup vs baseline: 2.4595x; 1.1956x over previous
//
#include <hip/hip_runtime.h>

typedef __attribute__((ext_vector_type(8))) short bf16x8;
typedef __attribute__((ext_vector_type(4))) float f32x4;

#define LPAD 2432
#define LKV  2382
#define NSEQ 2304
#define CDIM 512
#define LPSZ (4 * NSEQ * 8)  // l-partial entries per split (rows*heads)

__device__ __forceinline__ unsigned short f2bf(float f) {
  unsigned int u = __builtin_bit_cast(unsigned int, f);
  u += 0x7fffu + ((u >> 16) & 1u);
  return (unsigned short)(u >> 16);
}
__device__ __forceinline__ float bf2f(unsigned short s) {
  unsigned int u = ((unsigned int)s) << 16;
  return __builtin_bit_cast(float, u);
}
__device__ __forceinline__ f32x4 MFMA(bf16x8 a, bf16x8 b, f32x4 c) {
  return __builtin_amdgcn_mfma_f32_16x16x32_bf16(a, b, c, 0, 0, 0);
}
__device__ __forceinline__ void stage16(const unsigned short* g, unsigned short* l) {
  __builtin_amdgcn_global_load_lds((const __attribute__((address_space(1))) void*)g,
                                   (__attribute__((address_space(3))) void*)l, 16, 0, 0);
}
__device__ __forceinline__ unsigned int cvtpk(float a, float b) {
  unsigned int r;
  asm("v_cvt_pk_bf16_f32 %0, %1, %2" : "=v"(r) : "v"(a), "v"(b));
  return r;
}
// interleaved V^T column position within each 32-chunk
__device__ __forceinline__ int Fj(int j) {
  return (j & ~31) | ((j & 15) << 1) | ((j >> 4) & 1);
}

// ---------------- weight transpose + bf16 convert (LDS tiled, coalesced) ----
__device__ __forceinline__ void tr_tile(const float* __restrict__ in,
                                        unsigned short* __restrict__ out,
                                        int K, int N, int tk, int tn, int t) {
  __shared__ float T[32][33];
  int r = t >> 5, c = t & 31;
#pragma unroll
  for (int p = 0; p < 4; p++) {
    int rr = r + p * 8;
    T[rr][c] = in[(size_t)(tk * 32 + rr) * N + tn * 32 + c];
  }
  __syncthreads();
#pragma unroll
  for (int p = 0; p < 4; p++) {
    int rr = r + p * 8;
    out[(size_t)(tn * 32 + rr) * K + tk * 32 + c] = f2bf(T[c][rr]);
  }
}

__global__ void k_prep(const float* __restrict__ Wq, const float* __restrict__ Wkv,
                       const float* __restrict__ Wctx, const float* __restrict__ Wout,
                       unsigned short* __restrict__ WqT, unsigned short* __restrict__ WkvT,
                       unsigned short* __restrict__ WctxT, unsigned short* __restrict__ WoutT) {
  int bid = blockIdx.x, t = threadIdx.x;
  if (bid < 256) {
    tr_tile(Wq, WqT, 512, 512, bid >> 4, bid & 15, t);
  } else if (bid < 320) {
    int q = bid - 256;
    tr_tile(Wkv, WkvT, 512, 128, q >> 2, q & 3, t);
  } else if (bid < 416) {
    int q = bid - 320;
    tr_tile(Wctx, WctxT, 768, 128, q >> 2, q & 3, t);
  } else {
    int q = bid - 416;
    tr_tile(Wout, WoutT, 512, 512, q >> 4, q & 15, t);
  }
}

// ---------------- LN over C of x (B,C,N) -> xn bf16 (B*N, C) ----------------
// Single global read: phase 1 computes stats AND stashes x as bf16 in LDS.
__global__ void k_ln1(const float* __restrict__ x, const float* __restrict__ g,
                      unsigned short* __restrict__ xn) {
  int b = blockIdx.y;
  int i0 = blockIdx.x * 32;
  int t = threadIdx.x;
  int ii = t & 31, ci = t >> 5;
  const float* xb = x + (size_t)b * CDIM * NSEQ;
  __shared__ unsigned short Xs[32][514];
  __shared__ float ls[8][32], ls2[8][32];
  __shared__ float lmu[32], lrs[32];
  float s = 0.f, s2 = 0.f;
  for (int c = ci; c < CDIM; c += 8) {
    float v = xb[(size_t)c * NSEQ + i0 + ii];
    Xs[ii][c] = f2bf(v);
    s += v; s2 += v * v;
  }
  ls[ci][ii] = s; ls2[ci][ii] = s2;
  __syncthreads();
  if (t < 32) {
    float a = 0.f, a2 = 0.f;
    for (int q = 0; q < 8; q++) { a += ls[q][t]; a2 += ls2[q][t]; }
    float mu = a * (1.0f / 512.0f);
    float var = a2 * (1.0f / 512.0f) - mu * mu;
    lmu[t] = mu; lrs[t] = rsqrtf(var + 1e-5f);
  }
  __syncthreads();
  int rr = t >> 3, cl0 = (t & 7) * 8;
  float mu = lmu[rr], rs = lrs[rr];
  unsigned short* xrow = xn + (size_t)(b * NSEQ + i0 + rr) * CDIM;
#pragma unroll
  for (int cb = 0; cb < 8; cb++) {
    int c0 = cb * 64 + cl0;
    union { unsigned int w4[4]; uint4 u; } pk;
#pragma unroll
    for (int m = 0; m < 4; m++) {
      float v0 = (bf2f(Xs[rr][c0 + 2 * m]) - mu) * rs * g[c0 + 2 * m];
      float v1 = (bf2f(Xs[rr][c0 + 2 * m + 1]) - mu) * rs * g[c0 + 2 * m + 1];
      pk.w4[m] = cvtpk(v0, v1);
    }
    *reinterpret_cast<uint4*>(xrow + c0) = pk.u;
  }
}

// ---------------- context LN + projection; null row + zero pads ----------
__global__ void k_ctx(const float* __restrict__ ctx, const float* __restrict__ g,
                      const float* __restrict__ be, const unsigned short* __restrict__ WctxT,
                      const float* __restrict__ bctx, const float* __restrict__ null_kv,
                      unsigned short* __restrict__ kb, unsigned short* __restrict__ vt) {
  int b = blockIdx.y, j = blockIdx.x;
  int t = threadIdx.x;
  if (j == 77) {
    if (t < 64) kb[((size_t)b * LPAD + 77) * 64 + t] = f2bf(null_kv[t]);
    else vt[((size_t)b * 64 + (t - 64)) * LPAD + Fj(77)] = f2bf(null_kv[64 + (t - 64)]);
    return;
  }
  if (j > 77) {
    int jj = LKV + (j - 78);
    if (t < 64) kb[((size_t)b * LPAD + jj) * 64 + t] = 0;
    else vt[((size_t)b * 64 + (t - 64)) * LPAD + Fj(jj)] = 0;
    return;
  }
  __shared__ float row[768];
  __shared__ float red[4];
  const float* src = ctx + (size_t)(b * 77 + j) * 768;
  float s = 0.f, s2 = 0.f;
  for (int k = t; k < 768; k += 128) {
    float v = src[k];
    row[k] = v; s += v; s2 += v * v;
  }
  for (int o = 32; o; o >>= 1) { s += __shfl_xor(s, o); s2 += __shfl_xor(s2, o); }
  if ((t & 63) == 0) { red[(t >> 6) * 2] = s; red[(t >> 6) * 2 + 1] = s2; }
  __syncthreads();
  float S = red[0] + red[2], S2 = red[1] + red[3];
  float mu = S * (1.0f / 768.0f);
  float rs = rsqrtf(S2 * (1.0f / 768.0f) - mu * mu + 1e-5f);
  __syncthreads();
  for (int k = t; k < 768; k += 128) row[k] = (row[k] - mu) * rs * g[k] + be[k];
  __syncthreads();
  const uint4* w4 = reinterpret_cast<const uint4*>(WctxT + (size_t)t * 768);
  float acc = 0.f;
  for (int k8 = 0; k8 < 96; k8++) {
    union { uint4 u; unsigned short s[8]; } wv;
    wv.u = w4[k8];
#pragma unroll
    for (int e = 0; e < 8; e++) acc += row[k8 * 8 + e] * bf2f(wv.s[e]);
  }
  acc += bctx[t];
  if (t < 64) kb[((size_t)b * LPAD + j) * 64 + t] = f2bf(acc);
  else vt[((size_t)b * 64 + (t - 64)) * LPAD + Fj(j)] = f2bf(acc);
}

// ---------------- MFMA GEMM: BM=128 BN=64 BK=64, global_load_lds + dbuf -----
template <int MODE>
__global__ __launch_bounds__(256, 1) void k_gemm(
    const unsigned short* __restrict__ A, const unsigned short* __restrict__ BT0,
    const unsigned short* __restrict__ BT1, unsigned short* __restrict__ out_q,
    unsigned short* __restrict__ out_k, unsigned short* __restrict__ out_vt,
    unsigned short* __restrict__ out_proj) {
  int m0 = blockIdx.x * 128, n0 = blockIdx.y * 64;
  int t = threadIdx.x;
  int lane = t & 63, w = t >> 6;
  int wm = w >> 1, wn = w & 1;
  int G = lane >> 4, li = lane & 15, li7 = lane & 7;
  __shared__ __align__(16) unsigned short Al[2][8192];  // 128 x 64
  __shared__ __align__(16) unsigned short Bl[2][4096];  // 64 x 64
  const unsigned short* BT = (MODE == 0 && n0 >= 512) ? BT1 : BT0;
  int bn0 = (MODE == 0 && n0 >= 512) ? n0 - 512 : n0;

  f32x4 zero = {0.f, 0.f, 0.f, 0.f};
  f32x4 acc[4][2];
#pragma unroll
  for (int a = 0; a < 4; a++)
#pragma unroll
    for (int c = 0; c < 2; c++) acc[a][c] = zero;

#define STAGE_AB(buf, k0)                                                              \
  {                                                                                    \
    _Pragma("unroll") for (int p = 0; p < 4; p++) {                                    \
      int gA = p * 256 + t;                                                            \
      int ra = gA >> 3;                                                                \
      int ca = ((gA & 7) ^ (ra & 7)) * 8;                                              \
      stage16(A + (size_t)(m0 + ra) * 512 + (k0) + ca, &Al[buf][(p * 256 + w * 64) * 8]); \
    }                                                                                  \
    _Pragma("unroll") for (int p = 0; p < 2; p++) {                                    \
      int gB = p * 256 + t;                                                            \
      int rb = gB >> 3;                                                                \
      int cb = ((gB & 7) ^ (rb & 7)) * 8;                                              \
      stage16(BT + (size_t)(bn0 + rb) * 512 + (k0) + cb, &Bl[buf][(p * 256 + w * 64) * 8]); \
    }                                                                                  \
  }

  STAGE_AB(0, 0)
  __syncthreads();

  for (int u = 0; u < 8; u++) {
    int cur = u & 1, nxt = cur ^ 1;
    if (u < 7) STAGE_AB(nxt, (u + 1) * 64)
    const char* Ac = (const char*)Al[cur];
    const char* Bc = (const char*)Bl[cur];
#pragma unroll
    for (int ks = 0; ks < 2; ks++) {
      bf16x8 af[4], bfr[2];
#pragma unroll
      for (int f = 0; f < 4; f++)
        af[f] = *reinterpret_cast<const bf16x8*>(
            Ac + ((((wm * 64 + f * 16 + li) * 8) + ((ks * 4 + G) ^ li7)) << 4));
#pragma unroll
      for (int f = 0; f < 2; f++)
        bfr[f] = *reinterpret_cast<const bf16x8*>(
            Bc + ((((wn * 32 + f * 16 + li) * 8) + ((ks * 4 + G) ^ li7)) << 4));
#pragma unroll
      for (int fm = 0; fm < 4; fm++)
#pragma unroll
        for (int fn = 0; fn < 2; fn++)
          acc[fm][fn] = MFMA(af[fm], bfr[fn], acc[fm][fn]);
    }
    __syncthreads();
  }
#undef STAGE_AB

#pragma unroll
  for (int fm = 0; fm < 4; fm++)
#pragma unroll
    for (int fn = 0; fn < 2; fn++)
#pragma unroll
      for (int r = 0; r < 4; r++) {
        int row = m0 + wm * 64 + fm * 16 + G * 4 + r;
        int col = n0 + wn * 32 + fn * 16 + li;
        float v = acc[fm][fn][r];
        if (MODE == 0) {
          int b = row / NSEQ, i = row - b * NSEQ;
          // q pre-scaled by 1/sqrt(dh) * log2(e): softmax runs in exp2 domain
          if (col < 512) out_q[(size_t)row * 512 + col] = f2bf(v * 0.18033688011112042f);
          else if (col < 576) out_k[((size_t)b * LPAD + 78 + i) * 64 + (col - 512)] = f2bf(v);
          else out_vt[((size_t)b * 64 + (col - 576)) * LPAD + Fj(78 + i)] = f2bf(v);
        } else {
          out_proj[(size_t)row * 512 + col] = f2bf(v);
        }
      }
}

// ---------------- flash attention: 4-way KV split, KVBLK=32, 16KB LDS -------
// (R16's proven best: 82.8 us. V staged via global_load_lds; occupancy
// plateau ~35% is NOT LDS-capped (R19: 8KB no change) and V-unstaging puts
// L2 latency on the MFMA critical path (R19: +35 us). This is the local opt.)
__global__ __launch_bounds__(256, 4) void k_attn(
    const unsigned short* __restrict__ q, const unsigned short* __restrict__ kbuf,
    const unsigned short* __restrict__ vt, unsigned short* __restrict__ pO0,
    unsigned short* __restrict__ pO1, unsigned short* __restrict__ pO2,
    unsigned short* __restrict__ pO3, unsigned short* __restrict__ lp) {
  int bx = blockIdx.x;
  int it = bx >> 2, sp = bx & 3;
  int hh = blockIdx.y, b = blockIdx.z;
  int i0 = it * 32;
  int t = threadIdx.x;
  int w = t >> 6, lane = t & 63;
  int G = lane >> 4, li = lane & 15, li7 = lane & 7;
  int swzV = (li ^ (li >> 2)) & 3;
  int h = hh * 4 + w;

  __shared__ __align__(16) unsigned short Kl[2][2048];  // 32 rows x 64 d (4KB)
  __shared__ __align__(16) unsigned short Vl[2][2048];  // 64 rows x 32 j (4KB)

  int rk = t >> 3;
  int ck = ((t & 7) ^ (rk & 7)) * 8;
  int rv = t >> 2;
  int cv = ((t & 3) ^ ((rv ^ (rv >> 2)) & 3)) * 8;

  const unsigned short* kbase = kbuf + (size_t)b * LPAD * 64;
  const unsigned short* vbase = vt + (size_t)b * 64 * LPAD;

  bf16x8 qf[2][2];
#pragma unroll
  for (int fi = 0; fi < 2; fi++)
#pragma unroll
    for (int ks = 0; ks < 2; ks++)
      qf[fi][ks] = *reinterpret_cast<const bf16x8*>(
          q + (size_t)(b * NSEQ + i0 + fi * 16 + li) * CDIM + h * 64 + ks * 32 + G * 8);

  int jt0 = sp * 19;  // 76 tiles of 32 / 4 splits = 19 exact

  {
    int j0 = jt0 * 32;
    stage16(kbase + (size_t)(j0 + rk) * 64 + ck, &Kl[0][w * 512]);
    stage16(vbase + (size_t)rv * LPAD + j0 + cv, &Vl[0][w * 512]);
  }

  f32x4 zero = {0.f, 0.f, 0.f, 0.f};
  f32x4 OT[4][2];
#pragma unroll
  for (int fd = 0; fd < 4; fd++)
#pragma unroll
    for (int fi = 0; fi < 2; fi++) OT[fd][fi] = zero;
  float l_[2] = {0.f, 0.f};

  __syncthreads();

  for (int u = 0; u < 19; u++) {
    int jt = jt0 + u;
    int cur = u & 1, nxt = cur ^ 1;
    int j0 = jt * 32;
    if (u + 1 < 19) {
      int j1 = j0 + 32;
      stage16(kbase + (size_t)(j1 + rk) * 64 + ck, &Kl[nxt][w * 512]);
      stage16(vbase + (size_t)rv * LPAD + j1 + cv, &Vl[nxt][w * 512]);
    }
    const char* Kc = (const char*)Kl[cur];
    const char* Vc = (const char*)Vl[cur];

    f32x4 S[2][2];
#pragma unroll
    for (int fj = 0; fj < 2; fj++) { S[fj][0] = zero; S[fj][1] = zero; }
#pragma unroll
    for (int ks = 0; ks < 2; ks++) {
      bf16x8 kf[2];
#pragma unroll
      for (int fj = 0; fj < 2; fj++)
        kf[fj] = *reinterpret_cast<const bf16x8*>(
            Kc + ((((fj * 16 + li) * 8) + ((ks * 4 + G) ^ li7)) << 4));
#pragma unroll
      for (int fj = 0; fj < 2; fj++)
#pragma unroll
        for (int fi = 0; fi < 2; fi++)
          S[fj][fi] = MFMA(kf[fj], qf[fi][ks], S[fj][fi]);
    }
    if (j0 + 32 > LKV) {
#pragma unroll
      for (int fj = 0; fj < 2; fj++)
#pragma unroll
        for (int r = 0; r < 4; r++) {
          int jg = j0 + fj * 16 + G * 4 + r;
          if (jg >= LKV) { S[fj][0][r] = -1e30f; S[fj][1][r] = -1e30f; }
        }
    }
    bf16x8 pf[2];
#pragma unroll
    for (int fi = 0; fi < 2; fi++) {
      float e[2][4];
#pragma unroll
      for (int fj = 0; fj < 2; fj++)
#pragma unroll
        for (int r = 0; r < 4; r++) e[fj][r] = __builtin_exp2f(S[fj][fi][r]);
      float s0 = (e[0][0] + e[0][1]) + (e[0][2] + e[0][3]);
      float s1 = (e[1][0] + e[1][1]) + (e[1][2] + e[1][3]);
      l_[fi] += s0 + s1;
      union { unsigned int w4[4]; bf16x8 v; } u2;
#pragma unroll
      for (int m = 0; m < 4; m++) u2.w4[m] = cvtpk(e[0][m], e[1][m]);
      pf[fi] = u2.v;
    }
#pragma unroll
    for (int fd = 0; fd < 4; fd++) {
      bf16x8 uv = *reinterpret_cast<const bf16x8*>(
          Vc + (((fd * 16 + li) * 4 + (G ^ swzV)) << 4));
#pragma unroll
      for (int fi = 0; fi < 2; fi++) OT[fd][fi] = MFMA(uv, pf[fi], OT[fd][fi]);
    }
    __syncthreads();
  }

  unsigned short* pO = (sp == 0) ? pO0 : (sp == 1) ? pO1 : (sp == 2) ? pO2 : pO3;
#pragma unroll
  for (int fi = 0; fi < 2; fi++) {
    l_[fi] += __shfl_xor(l_[fi], 16);
    l_[fi] += __shfl_xor(l_[fi], 32);
    int row = b * NSEQ + i0 + fi * 16 + li;
    if (G == 0) lp[sp * LPSZ + row * 8 + h] = f2bf(l_[fi]);
#pragma unroll
    for (int fd = 0; fd < 4; fd++) {
      union { unsigned int w2[2]; uint2 u2; } pk;
      pk.w2[0] = cvtpk(OT[fd][fi][0], OT[fd][fi][1]);
      pk.w2[1] = cvtpk(OT[fd][fi][2], OT[fd][fi][3]);
      *reinterpret_cast<uint2*>(pO + (size_t)row * CDIM + h * 64 + fd * 16 + G * 4) = pk.u2;
    }
  }
}

// ---------------- merge the four KV-split partials ----------------
__global__ void k_merge(unsigned short* __restrict__ pO0,
                        const unsigned short* __restrict__ pO1,
                        const unsigned short* __restrict__ pO2,
                        const unsigned short* __restrict__ pO3,
                        const unsigned short* __restrict__ lp) {
  int c = blockIdx.x * 256 + threadIdx.x;
  size_t base = (size_t)c * 8;
  int row = (int)(base >> 9);
  int h = (int)((base >> 6) & 7);
  int li = row * 8 + h;
  float l = bf2f(lp[li]) + bf2f(lp[LPSZ + li]) + bf2f(lp[2 * LPSZ + li]) + bf2f(lp[3 * LPSZ + li]);
  float inv = 1.0f / l;
  union { uint4 u; unsigned short s[8]; } a0, a1, a2, a3, o;
  a0.u = *reinterpret_cast<const uint4*>(pO0 + base);
  a1.u = *reinterpret_cast<const uint4*>(pO1 + base);
  a2.u = *reinterpret_cast<const uint4*>(pO2 + base);
  a3.u = *reinterpret_cast<const uint4*>(pO3 + base);
  unsigned int* ow = reinterpret_cast<unsigned int*>(&o.u);
#pragma unroll
  for (int m = 0; m < 4; m++) {
    float v0 = (bf2f(a0.s[2 * m]) + bf2f(a1.s[2 * m]) + bf2f(a2.s[2 * m]) + bf2f(a3.s[2 * m])) * inv;
    float v1 = (bf2f(a0.s[2 * m + 1]) + bf2f(a1.s[2 * m + 1]) + bf2f(a2.s[2 * m + 1]) +
                bf2f(a3.s[2 * m + 1])) * inv;
    ow[m] = cvtpk(v0, v1);
  }
  *reinterpret_cast<uint4*>(pO0 + base) = o.u;
}

// ---------------- per-row LN stats of proj (bf16, coalesced) ----------------
__global__ void k_stats(const unsigned short* __restrict__ proj, float* __restrict__ musig) {
  int w = threadIdx.x >> 6, lane = threadIdx.x & 63;
  int row = blockIdx.x * 4 + w;
  union { uint4 u; unsigned short s[8]; } a;
  a.u = *reinterpret_cast<const uint4*>(proj + (size_t)row * CDIM + lane * 8);
  float s = 0.f, s2 = 0.f;
#pragma unroll
  for (int m = 0; m < 8; m++) {
    float v = bf2f(a.s[m]);
    s += v; s2 += v * v;
  }
  for (int o = 32; o; o >>= 1) { s += __shfl_xor(s, o); s2 += __shfl_xor(s2, o); }
  if (lane == 0) {
    float mu = s * (1.0f / 512.0f);
    float var = s2 * (1.0f / 512.0f) - mu * mu;
    musig[row] = mu;
    musig[4 * NSEQ + row] = rsqrtf(var + 1e-5f);
  }
}

// ---------------- final LN + residual, LDS-transposed, fully coalesced ------
__global__ void k_final2(const unsigned short* __restrict__ proj, const float* __restrict__ musig,
                         const float* __restrict__ g, const float* __restrict__ x,
                         float* __restrict__ y) {
  int i0 = blockIdx.x * 32, c0 = blockIdx.y * 64, b = blockIdx.z;
  int t = threadIdx.x;
  __shared__ float lds[32][65];
  {
    int il = t >> 3, cB = (t & 7) * 8;
    union { uint4 u; unsigned short s[8]; } a;
    a.u = *reinterpret_cast<const uint4*>(proj + (size_t)(b * NSEQ + i0 + il) * CDIM + c0 + cB);
#pragma unroll
    for (int m = 0; m < 8; m++) lds[il][cB + m] = bf2f(a.s[m]);
  }
  __syncthreads();
  int ii = t & 31, cg = t >> 5;
  float mu = musig[b * NSEQ + i0 + ii];
  float rs = musig[4 * NSEQ + b * NSEQ + i0 + ii];
  const float* xb = x + (size_t)b * CDIM * NSEQ;
  float* yb = y + (size_t)b * CDIM * NSEQ;
#pragma unroll
  for (int cc = 0; cc < 8; cc++) {
    int cl = cg * 8 + cc;
    int c = c0 + cl;
    float v = lds[ii][cl];
    yb[(size_t)c * NSEQ + i0 + ii] = xb[(size_t)c * NSEQ + i0 + ii] + (v - mu) * rs * g[c];
  }
}

extern "C" void kernel_launch(void* const* d_in, const int* in_sizes, int n_in,
                              void* d_out, int out_size, void* d_ws, size_t ws_size,
                              hipStream_t stream) {
  const float* x       = (const float*)d_in[0];
  const float* context = (const float*)d_in[1];
  const float* ngamma  = (const float*)d_in[2];
  const float* null_kv = (const float*)d_in[3];
  const float* Wq      = (const float*)d_in[4];
  const float* Wkv     = (const float*)d_in[5];
  const float* clng    = (const float*)d_in[6];
  const float* clnb    = (const float*)d_in[7];
  const float* Wctx    = (const float*)d_in[8];
  const float* bctx    = (const float*)d_in[9];
  const float* Wout    = (const float*)d_in[10];
  const float* olng    = (const float*)d_in[11];
  float* y = (float*)d_out;
  char* ws = (char*)d_ws;

  unsigned short* xn    = (unsigned short*)(ws);              // 9437184 B (pO1 during attn)
  unsigned short* qb    = (unsigned short*)(ws + 9437184);    // 9437184 B
  unsigned short* proj  = (unsigned short*)(ws);              // bf16, aliases xn (dead by then)
  unsigned short* aoutb = (unsigned short*)(ws + 18874368);   // 9437184 B (pO0 -> merged)
  float* musig          = (float*)(ws + 18874368);            // aliases aoutb (dead after gemm1)
  unsigned short* kb    = (unsigned short*)(ws + 28311552);   // 1245184 B
  unsigned short* vtb   = (unsigned short*)(ws + 29556736);   // 1245184 B
  unsigned short* WqT   = (unsigned short*)(ws + 30801920);   // 524288 B
  unsigned short* WkvT  = (unsigned short*)(ws + 31326208);   // 131072 B
  unsigned short* WctxT = (unsigned short*)(ws + 31457280);   // 196608 B
  unsigned short* WoutT = (unsigned short*)(ws + 31653888);   // 524288 B
  // bf16 l-partials: 4 x 73728 x 2B = 589824 B, overlay WqT+WkvT (dead after gemm0)
  unsigned short* lpart = (unsigned short*)(ws + 30801920);
  // partials 2,3 live in d_out (18874368 B); k_final2 fully rewrites y after.
  unsigned short* pO2   = (unsigned short*)d_out;
  unsigned short* pO3   = (unsigned short*)d_out + 4718592;

  k_prep<<<dim3(672), dim3(256), 0, stream>>>(Wq, Wkv, Wctx, Wout, WqT, WkvT, WctxT, WoutT);
  k_ln1<<<dim3(72, 4), dim3(256), 0, stream>>>(x, ngamma, xn);
  k_ctx<<<dim3(128, 4), dim3(128), 0, stream>>>(context, clng, clnb, WctxT, bctx, null_kv, kb, vtb);
  k_gemm<0><<<dim3(72, 10), dim3(256), 0, stream>>>(xn, WqT, WkvT, qb, kb, vtb, nullptr);
  k_attn<<<dim3(288, 2, 4), dim3(256), 0, stream>>>(qb, kb, vtb, aoutb, xn, pO2, pO3, lpart);
  k_merge<<<dim3(2304), dim3(256), 0, stream>>>(aoutb, xn, pO2, pO3, lpart);
  k_gemm<1><<<dim3(72, 8), dim3(256), 0, stream>>>(aoutb, WoutT, nullptr, nullptr, nullptr, nullptr, proj);
  k_stats<<<dim3(2304), dim3(256), 0, stream>>>(proj, musig);
  k_final2<<<dim3(72, 8, 4), dim3(256), 0, stream>>>(proj, musig, olng, x, y);
}

// Round 21
// 146.914 us; speedup vs baseline: 2.8073x; 1.1414x over previous
//
#include <hip/hip_runtime.h>

typedef __attribute__((ext_vector_type(8))) short bf16x8;
typedef __attribute__((ext_vector_type(4))) float f32x4;

#define LPAD 2432
#define LKV  2382
#define NSEQ 2304
#define CDIM 512
#define LPSZ (4 * NSEQ * 8)  // l-partial entries per split (rows*heads)

__device__ __forceinline__ unsigned short f2bf(float f) {
  unsigned int u = __builtin_bit_cast(unsigned int, f);
  u += 0x7fffu + ((u >> 16) & 1u);
  return (unsigned short)(u >> 16);
}
__device__ __forceinline__ float bf2f(unsigned short s) {
  unsigned int u = ((unsigned int)s) << 16;
  return __builtin_bit_cast(float, u);
}
__device__ __forceinline__ f32x4 MFMA(bf16x8 a, bf16x8 b, f32x4 c) {
  return __builtin_amdgcn_mfma_f32_16x16x32_bf16(a, b, c, 0, 0, 0);
}
__device__ __forceinline__ void stage16(const unsigned short* g, unsigned short* l) {
  __builtin_amdgcn_global_load_lds((const __attribute__((address_space(1))) void*)g,
                                   (__attribute__((address_space(3))) void*)l, 16, 0, 0);
}
__device__ __forceinline__ unsigned int cvtpk(float a, float b) {
  unsigned int r;
  asm("v_cvt_pk_bf16_f32 %0, %1, %2" : "=v"(r) : "v"(a), "v"(b));
  return r;
}
// interleaved V^T column position within each 32-chunk
__device__ __forceinline__ int Fj(int j) {
  return (j & ~31) | ((j & 15) << 1) | ((j >> 4) & 1);
}

__device__ __forceinline__ void tr_tile2(const float* __restrict__ in,
                                         unsigned short* __restrict__ out,
                                         int K, int N, int tk, int tn, int t,
                                         float (*T)[33]) {
  int r = t >> 5, c = t & 31;
#pragma unroll
  for (int p = 0; p < 4; p++) {
    int rr = r + p * 8;
    T[rr][c] = in[(size_t)(tk * 32 + rr) * N + tn * 32 + c];
  }
  __syncthreads();
#pragma unroll
  for (int p = 0; p < 4; p++) {
    int rr = r + p * 8;
    out[(size_t)(tn * 32 + rr) * K + tk * 32 + c] = f2bf(T[c][rr]);
  }
}

// ---------------- fused pre-pass: weight transposes + ln1 + ctx ----------------
// bid <576: transpose Wq(256)/Wkv(64)/Wout(256) tiles.
// bid 576..863: LN over C of x -> xn (single global read, LDS bf16 stash).
// bid 864..1375: context LN + projection (reads Wctx f32 directly, coalesced
// across t -> no WctxT dependency, so all three stages fuse into one launch).
__global__ void k_pre(const float* __restrict__ Wq, const float* __restrict__ Wkv,
                      const float* __restrict__ Wout, const float* __restrict__ x,
                      const float* __restrict__ ngamma, const float* __restrict__ ctx,
                      const float* __restrict__ clng, const float* __restrict__ clnb,
                      const float* __restrict__ Wctx, const float* __restrict__ bctx,
                      const float* __restrict__ null_kv,
                      unsigned short* __restrict__ WqT, unsigned short* __restrict__ WkvT,
                      unsigned short* __restrict__ WoutT, unsigned short* __restrict__ xn,
                      unsigned short* __restrict__ kb, unsigned short* __restrict__ vt) {
  __shared__ __align__(16) char smem[35200];
  int bid = blockIdx.x, t = threadIdx.x;
  if (bid < 576) {
    float (*T)[33] = reinterpret_cast<float(*)[33]>(smem);
    if (bid < 256) {
      tr_tile2(Wq, WqT, 512, 512, bid >> 4, bid & 15, t, T);
    } else if (bid < 320) {
      int q2 = bid - 256;
      tr_tile2(Wkv, WkvT, 512, 128, q2 >> 2, q2 & 3, t, T);
    } else {
      int q2 = bid - 320;
      tr_tile2(Wout, WoutT, 512, 512, q2 >> 4, q2 & 15, t, T);
    }
    return;
  }
  if (bid < 864) {
    // ---- ln1 ----
    int idx = bid - 576;
    int i0 = (idx % 72) * 32, b = idx / 72;
    unsigned short (*Xs)[514] = reinterpret_cast<unsigned short(*)[514]>(smem);
    float (*ls)[32] = reinterpret_cast<float (*)[32]>(smem + 32896);
    float (*ls2)[32] = reinterpret_cast<float (*)[32]>(smem + 33920);
    float* lmu = reinterpret_cast<float*>(smem + 34944);
    float* lrs = reinterpret_cast<float*>(smem + 35072);
    int ii = t & 31, ci = t >> 5;
    const float* xb = x + (size_t)b * CDIM * NSEQ;
    float s = 0.f, s2 = 0.f;
    for (int c = ci; c < CDIM; c += 8) {
      float v = xb[(size_t)c * NSEQ + i0 + ii];
      Xs[ii][c] = f2bf(v);
      s += v; s2 += v * v;
    }
    ls[ci][ii] = s; ls2[ci][ii] = s2;
    __syncthreads();
    if (t < 32) {
      float a = 0.f, a2 = 0.f;
      for (int q2 = 0; q2 < 8; q2++) { a += ls[q2][t]; a2 += ls2[q2][t]; }
      float mu = a * (1.0f / 512.0f);
      float var = a2 * (1.0f / 512.0f) - mu * mu;
      lmu[t] = mu; lrs[t] = rsqrtf(var + 1e-5f);
    }
    __syncthreads();
    int rr = t >> 3, cl0 = (t & 7) * 8;
    float mu = lmu[rr], rs = lrs[rr];
    unsigned short* xrow = xn + (size_t)(b * NSEQ + i0 + rr) * CDIM;
#pragma unroll
    for (int cb = 0; cb < 8; cb++) {
      int c0 = cb * 64 + cl0;
      union { unsigned int w4[4]; uint4 u; } pk;
#pragma unroll
      for (int m = 0; m < 4; m++) {
        float v0 = (bf2f(Xs[rr][c0 + 2 * m]) - mu) * rs * ngamma[c0 + 2 * m];
        float v1 = (bf2f(Xs[rr][c0 + 2 * m + 1]) - mu) * rs * ngamma[c0 + 2 * m + 1];
        pk.w4[m] = cvtpk(v0, v1);
      }
      *reinterpret_cast<uint4*>(xrow + c0) = pk.u;
    }
    return;
  }
  // ---- ctx ----
  int idx = bid - 864;
  int j = idx & 127, b = idx >> 7;
  if (j == 77) {
    if (t < 64) kb[((size_t)b * LPAD + 77) * 64 + t] = f2bf(null_kv[t]);
    else if (t < 128) vt[((size_t)b * 64 + (t - 64)) * LPAD + Fj(77)] = f2bf(null_kv[64 + (t - 64)]);
    return;
  }
  if (j > 77) {
    int jj = LKV + (j - 78);
    if (t < 64) kb[((size_t)b * LPAD + jj) * 64 + t] = 0;
    else if (t < 128) vt[((size_t)b * 64 + (t - 64)) * LPAD + Fj(jj)] = 0;
    return;
  }
  float* row = reinterpret_cast<float*>(smem);
  float* red = reinterpret_cast<float*>(smem + 3072);
  const float* src = ctx + (size_t)(b * 77 + j) * 768;
  float s = 0.f, s2 = 0.f;
  for (int k = t; k < 768; k += 256) {
    float v = src[k];
    row[k] = v; s += v; s2 += v * v;
  }
  for (int o = 32; o; o >>= 1) { s += __shfl_xor(s, o); s2 += __shfl_xor(s2, o); }
  if ((t & 63) == 0) { red[(t >> 6) * 2] = s; red[(t >> 6) * 2 + 1] = s2; }
  __syncthreads();
  float S = red[0] + red[2] + red[4] + red[6];
  float S2 = red[1] + red[3] + red[5] + red[7];
  float mu = S * (1.0f / 768.0f);
  float rs = rsqrtf(S2 * (1.0f / 768.0f) - mu * mu + 1e-5f);
  __syncthreads();
  for (int k = t; k < 768; k += 256) row[k] = (row[k] - mu) * rs * clng[k] + clnb[k];
  __syncthreads();
  if (t < 128) {
    float acc = 0.f;
    for (int k8 = 0; k8 < 96; k8++) {
#pragma unroll
      for (int e = 0; e < 8; e++) {
        int k = k8 * 8 + e;
        acc += row[k] * Wctx[(size_t)k * 128 + t];
      }
    }
    acc += bctx[t];
    if (t < 64) kb[((size_t)b * LPAD + j) * 64 + t] = f2bf(acc);
    else vt[((size_t)b * 64 + (t - 64)) * LPAD + Fj(j)] = f2bf(acc);
  }
}

// ---------------- MFMA GEMM: BM=128 BN=64 BK=64, global_load_lds + dbuf -----
template <int MODE>
__global__ __launch_bounds__(256, 1) void k_gemm(
    const unsigned short* __restrict__ A, const unsigned short* __restrict__ BT0,
    const unsigned short* __restrict__ BT1, unsigned short* __restrict__ out_q,
    unsigned short* __restrict__ out_k, unsigned short* __restrict__ out_vt,
    unsigned short* __restrict__ out_proj) {
  int m0 = blockIdx.x * 128, n0 = blockIdx.y * 64;
  int t = threadIdx.x;
  int lane = t & 63, w = t >> 6;
  int wm = w >> 1, wn = w & 1;
  int G = lane >> 4, li = lane & 15, li7 = lane & 7;
  __shared__ __align__(16) unsigned short Al[2][8192];  // 128 x 64
  __shared__ __align__(16) unsigned short Bl[2][4096];  // 64 x 64
  const unsigned short* BT = (MODE == 0 && n0 >= 512) ? BT1 : BT0;
  int bn0 = (MODE == 0 && n0 >= 512) ? n0 - 512 : n0;

  f32x4 zero = {0.f, 0.f, 0.f, 0.f};
  f32x4 acc[4][2];
#pragma unroll
  for (int a = 0; a < 4; a++)
#pragma unroll
    for (int c = 0; c < 2; c++) acc[a][c] = zero;

#define STAGE_AB(buf, k0)                                                              \
  {                                                                                    \
    _Pragma("unroll") for (int p = 0; p < 4; p++) {                                    \
      int gA = p * 256 + t;                                                            \
      int ra = gA >> 3;                                                                \
      int ca = ((gA & 7) ^ (ra & 7)) * 8;                                              \
      stage16(A + (size_t)(m0 + ra) * 512 + (k0) + ca, &Al[buf][(p * 256 + w * 64) * 8]); \
    }                                                                                  \
    _Pragma("unroll") for (int p = 0; p < 2; p++) {                                    \
      int gB = p * 256 + t;                                                            \
      int rb = gB >> 3;                                                                \
      int cb = ((gB & 7) ^ (rb & 7)) * 8;                                              \
      stage16(BT + (size_t)(bn0 + rb) * 512 + (k0) + cb, &Bl[buf][(p * 256 + w * 64) * 8]); \
    }                                                                                  \
  }

  STAGE_AB(0, 0)
  __syncthreads();

  for (int u = 0; u < 8; u++) {
    int cur = u & 1, nxt = cur ^ 1;
    if (u < 7) STAGE_AB(nxt, (u + 1) * 64)
    const char* Ac = (const char*)Al[cur];
    const char* Bc = (const char*)Bl[cur];
#pragma unroll
    for (int ks = 0; ks < 2; ks++) {
      bf16x8 af[4], bfr[2];
#pragma unroll
      for (int f = 0; f < 4; f++)
        af[f] = *reinterpret_cast<const bf16x8*>(
            Ac + ((((wm * 64 + f * 16 + li) * 8) + ((ks * 4 + G) ^ li7)) << 4));
#pragma unroll
      for (int f = 0; f < 2; f++)
        bfr[f] = *reinterpret_cast<const bf16x8*>(
            Bc + ((((wn * 32 + f * 16 + li) * 8) + ((ks * 4 + G) ^ li7)) << 4));
#pragma unroll
      for (int fm = 0; fm < 4; fm++)
#pragma unroll
        for (int fn = 0; fn < 2; fn++)
          acc[fm][fn] = MFMA(af[fm], bfr[fn], acc[fm][fn]);
    }
    __syncthreads();
  }
#undef STAGE_AB

#pragma unroll
  for (int fm = 0; fm < 4; fm++)
#pragma unroll
    for (int fn = 0; fn < 2; fn++)
#pragma unroll
      for (int r = 0; r < 4; r++) {
        int row = m0 + wm * 64 + fm * 16 + G * 4 + r;
        int col = n0 + wn * 32 + fn * 16 + li;
        float v = acc[fm][fn][r];
        if (MODE == 0) {
          int b = row / NSEQ, i = row - b * NSEQ;
          // q pre-scaled by 1/sqrt(dh) * log2(e): softmax runs in exp2 domain
          if (col < 512) out_q[(size_t)row * 512 + col] = f2bf(v * 0.18033688011112042f);
          else if (col < 576) out_k[((size_t)b * LPAD + 78 + i) * 64 + (col - 512)] = f2bf(v);
          else out_vt[((size_t)b * 64 + (col - 576)) * LPAD + Fj(78 + i)] = f2bf(v);
        } else {
          out_proj[(size_t)row * 512 + col] = f2bf(v);
        }
      }
}

// ---------------- flash attention: 4-way KV split, KVBLK=32, 16KB LDS -------
// (R16/R20 proven best: 82.6 us.)
__global__ __launch_bounds__(256, 4) void k_attn(
    const unsigned short* __restrict__ q, const unsigned short* __restrict__ kbuf,
    const unsigned short* __restrict__ vt, unsigned short* __restrict__ pO0,
    unsigned short* __restrict__ pO1, unsigned short* __restrict__ pO2,
    unsigned short* __restrict__ pO3, unsigned short* __restrict__ lp) {
  int bx = blockIdx.x;
  int it = bx >> 2, sp = bx & 3;
  int hh = blockIdx.y, b = blockIdx.z;
  int i0 = it * 32;
  int t = threadIdx.x;
  int w = t >> 6, lane = t & 63;
  int G = lane >> 4, li = lane & 15, li7 = lane & 7;
  int swzV = (li ^ (li >> 2)) & 3;
  int h = hh * 4 + w;

  __shared__ __align__(16) unsigned short Kl[2][2048];  // 32 rows x 64 d (4KB)
  __shared__ __align__(16) unsigned short Vl[2][2048];  // 64 rows x 32 j (4KB)

  int rk = t >> 3;
  int ck = ((t & 7) ^ (rk & 7)) * 8;
  int rv = t >> 2;
  int cv = ((t & 3) ^ ((rv ^ (rv >> 2)) & 3)) * 8;

  const unsigned short* kbase = kbuf + (size_t)b * LPAD * 64;
  const unsigned short* vbase = vt + (size_t)b * 64 * LPAD;

  bf16x8 qf[2][2];
#pragma unroll
  for (int fi = 0; fi < 2; fi++)
#pragma unroll
    for (int ks = 0; ks < 2; ks++)
      qf[fi][ks] = *reinterpret_cast<const bf16x8*>(
          q + (size_t)(b * NSEQ + i0 + fi * 16 + li) * CDIM + h * 64 + ks * 32 + G * 8);

  int jt0 = sp * 19;  // 76 tiles of 32 / 4 splits = 19 exact

  {
    int j0 = jt0 * 32;
    stage16(kbase + (size_t)(j0 + rk) * 64 + ck, &Kl[0][w * 512]);
    stage16(vbase + (size_t)rv * LPAD + j0 + cv, &Vl[0][w * 512]);
  }

  f32x4 zero = {0.f, 0.f, 0.f, 0.f};
  f32x4 OT[4][2];
#pragma unroll
  for (int fd = 0; fd < 4; fd++)
#pragma unroll
    for (int fi = 0; fi < 2; fi++) OT[fd][fi] = zero;
  float l_[2] = {0.f, 0.f};

  __syncthreads();

  for (int u = 0; u < 19; u++) {
    int jt = jt0 + u;
    int cur = u & 1, nxt = cur ^ 1;
    int j0 = jt * 32;
    if (u + 1 < 19) {
      int j1 = j0 + 32;
      stage16(kbase + (size_t)(j1 + rk) * 64 + ck, &Kl[nxt][w * 512]);
      stage16(vbase + (size_t)rv * LPAD + j1 + cv, &Vl[nxt][w * 512]);
    }
    const char* Kc = (const char*)Kl[cur];
    const char* Vc = (const char*)Vl[cur];

    f32x4 S[2][2];
#pragma unroll
    for (int fj = 0; fj < 2; fj++) { S[fj][0] = zero; S[fj][1] = zero; }
#pragma unroll
    for (int ks = 0; ks < 2; ks++) {
      bf16x8 kf[2];
#pragma unroll
      for (int fj = 0; fj < 2; fj++)
        kf[fj] = *reinterpret_cast<const bf16x8*>(
            Kc + ((((fj * 16 + li) * 8) + ((ks * 4 + G) ^ li7)) << 4));
#pragma unroll
      for (int fj = 0; fj < 2; fj++)
#pragma unroll
        for (int fi = 0; fi < 2; fi++)
          S[fj][fi] = MFMA(kf[fj], qf[fi][ks], S[fj][fi]);
    }
    if (j0 + 32 > LKV) {
#pragma unroll
      for (int fj = 0; fj < 2; fj++)
#pragma unroll
        for (int r = 0; r < 4; r++) {
          int jg = j0 + fj * 16 + G * 4 + r;
          if (jg >= LKV) { S[fj][0][r] = -1e30f; S[fj][1][r] = -1e30f; }
        }
    }
    bf16x8 pf[2];
#pragma unroll
    for (int fi = 0; fi < 2; fi++) {
      float e[2][4];
#pragma unroll
      for (int fj = 0; fj < 2; fj++)
#pragma unroll
        for (int r = 0; r < 4; r++) e[fj][r] = __builtin_exp2f(S[fj][fi][r]);
      float s0 = (e[0][0] + e[0][1]) + (e[0][2] + e[0][3]);
      float s1 = (e[1][0] + e[1][1]) + (e[1][2] + e[1][3]);
      l_[fi] += s0 + s1;
      union { unsigned int w4[4]; bf16x8 v; } u2;
#pragma unroll
      for (int m = 0; m < 4; m++) u2.w4[m] = cvtpk(e[0][m], e[1][m]);
      pf[fi] = u2.v;
    }
#pragma unroll
    for (int fd = 0; fd < 4; fd++) {
      bf16x8 uv = *reinterpret_cast<const bf16x8*>(
          Vc + (((fd * 16 + li) * 4 + (G ^ swzV)) << 4));
#pragma unroll
      for (int fi = 0; fi < 2; fi++) OT[fd][fi] = MFMA(uv, pf[fi], OT[fd][fi]);
    }
    __syncthreads();
  }

  unsigned short* pO = (sp == 0) ? pO0 : (sp == 1) ? pO1 : (sp == 2) ? pO2 : pO3;
#pragma unroll
  for (int fi = 0; fi < 2; fi++) {
    l_[fi] += __shfl_xor(l_[fi], 16);
    l_[fi] += __shfl_xor(l_[fi], 32);
    int row = b * NSEQ + i0 + fi * 16 + li;
    if (G == 0) lp[sp * LPSZ + row * 8 + h] = f2bf(l_[fi]);
#pragma unroll
    for (int fd = 0; fd < 4; fd++) {
      union { unsigned int w2[2]; uint2 u2; } pk;
      pk.w2[0] = cvtpk(OT[fd][fi][0], OT[fd][fi][1]);
      pk.w2[1] = cvtpk(OT[fd][fi][2], OT[fd][fi][3]);
      *reinterpret_cast<uint2*>(pO + (size_t)row * CDIM + h * 64 + fd * 16 + G * 4) = pk.u2;
    }
  }
}

// ---------------- merge the four KV-split partials ----------------
__global__ void k_merge(unsigned short* __restrict__ pO0,
                        const unsigned short* __restrict__ pO1,
                        const unsigned short* __restrict__ pO2,
                        const unsigned short* __restrict__ pO3,
                        const unsigned short* __restrict__ lp) {
  int c = blockIdx.x * 256 + threadIdx.x;
  size_t base = (size_t)c * 8;
  int row = (int)(base >> 9);
  int h = (int)((base >> 6) & 7);
  int li = row * 8 + h;
  float l = bf2f(lp[li]) + bf2f(lp[LPSZ + li]) + bf2f(lp[2 * LPSZ + li]) + bf2f(lp[3 * LPSZ + li]);
  float inv = 1.0f / l;
  union { uint4 u; unsigned short s[8]; } a0, a1, a2, a3, o;
  a0.u = *reinterpret_cast<const uint4*>(pO0 + base);
  a1.u = *reinterpret_cast<const uint4*>(pO1 + base);
  a2.u = *reinterpret_cast<const uint4*>(pO2 + base);
  a3.u = *reinterpret_cast<const uint4*>(pO3 + base);
  unsigned int* ow = reinterpret_cast<unsigned int*>(&o.u);
#pragma unroll
  for (int m = 0; m < 4; m++) {
    float v0 = (bf2f(a0.s[2 * m]) + bf2f(a1.s[2 * m]) + bf2f(a2.s[2 * m]) + bf2f(a3.s[2 * m])) * inv;
    float v1 = (bf2f(a0.s[2 * m + 1]) + bf2f(a1.s[2 * m + 1]) + bf2f(a2.s[2 * m + 1]) +
                bf2f(a3.s[2 * m + 1])) * inv;
    ow[m] = cvtpk(v0, v1);
  }
  *reinterpret_cast<uint4*>(pO0 + base) = o.u;
}

// ---------------- fused LN stats + final LN + residual ----------------
// Grid (144,4), 16 rows/block. One proj read (LDS stash), row stats via
// 16-lane shfl reduce, then transposed coalesced y-write (stride-514 LDS,
// 2-way-free banks).
__global__ void k_fin(const unsigned short* __restrict__ proj, const float* __restrict__ g,
                      const float* __restrict__ x, float* __restrict__ y) {
  int i0 = blockIdx.x * 16, b = blockIdx.y;
  int t = threadIdx.x;
  __shared__ unsigned short Ps[16][514];
  __shared__ float lmu[16], lrs[16];
  int rr = t >> 4, c8 = (t & 15) * 8;
  const unsigned short* prow = proj + (size_t)(b * NSEQ + i0 + rr) * CDIM;
  float s = 0.f, s2 = 0.f;
#pragma unroll
  for (int cb = 0; cb < 4; cb++) {
    int c0 = cb * 128 + c8;
    union { uint4 u; unsigned int w[4]; unsigned short sv[8]; } a;
    a.u = *reinterpret_cast<const uint4*>(prow + c0);
    unsigned int* P32 = reinterpret_cast<unsigned int*>(&Ps[rr][c0]);
#pragma unroll
    for (int m = 0; m < 4; m++) P32[m] = a.w[m];
#pragma unroll
    for (int m = 0; m < 8; m++) { float v = bf2f(a.sv[m]); s += v; s2 += v * v; }
  }
  s += __shfl_xor(s, 1); s2 += __shfl_xor(s2, 1);
  s += __shfl_xor(s, 2); s2 += __shfl_xor(s2, 2);
  s += __shfl_xor(s, 4); s2 += __shfl_xor(s2, 4);
  s += __shfl_xor(s, 8); s2 += __shfl_xor(s2, 8);
  if ((t & 15) == 0) {
    float mu = s * (1.0f / 512.0f);
    float var = s2 * (1.0f / 512.0f) - mu * mu;
    lmu[rr] = mu; lrs[rr] = rsqrtf(var + 1e-5f);
  }
  __syncthreads();
  int ii = t & 15, cg = t >> 4;
  float mu = lmu[ii], rs = lrs[ii];
  const float* xb = x + (size_t)b * CDIM * NSEQ;
  float* yb = y + (size_t)b * CDIM * NSEQ;
#pragma unroll 4
  for (int cc = 0; cc < 32; cc++) {
    int c = cg * 32 + cc;
    float v = bf2f(Ps[ii][c]);
    yb[(size_t)c * NSEQ + i0 + ii] = xb[(size_t)c * NSEQ + i0 + ii] + (v - mu) * rs * g[c];
  }
}

extern "C" void kernel_launch(void* const* d_in, const int* in_sizes, int n_in,
                              void* d_out, int out_size, void* d_ws, size_t ws_size,
                              hipStream_t stream) {
  const float* x       = (const float*)d_in[0];
  const float* context = (const float*)d_in[1];
  const float* ngamma  = (const float*)d_in[2];
  const float* null_kv = (const float*)d_in[3];
  const float* Wq      = (const float*)d_in[4];
  const float* Wkv     = (const float*)d_in[5];
  const float* clng    = (const float*)d_in[6];
  const float* clnb    = (const float*)d_in[7];
  const float* Wctx    = (const float*)d_in[8];
  const float* bctx    = (const float*)d_in[9];
  const float* Wout    = (const float*)d_in[10];
  const float* olng    = (const float*)d_in[11];
  float* y = (float*)d_out;
  char* ws = (char*)d_ws;

  unsigned short* xn    = (unsigned short*)(ws);              // 9437184 B (pO1 during attn)
  unsigned short* qb    = (unsigned short*)(ws + 9437184);    // 9437184 B
  unsigned short* proj  = (unsigned short*)(ws);              // bf16, aliases xn (dead by then)
  unsigned short* aoutb = (unsigned short*)(ws + 18874368);   // 9437184 B (pO0 -> merged)
  unsigned short* kb    = (unsigned short*)(ws + 28311552);   // 1245184 B
  unsigned short* vtb   = (unsigned short*)(ws + 29556736);   // 1245184 B
  unsigned short* WqT   = (unsigned short*)(ws + 30801920);   // 524288 B
  unsigned short* WkvT  = (unsigned short*)(ws + 31326208);   // 131072 B
  unsigned short* WoutT = (unsigned short*)(ws + 31653888);   // 524288 B
  // bf16 l-partials: 4 x 73728 x 2B = 589824 B, overlay WqT+WkvT (dead after gemm0)
  unsigned short* lpart = (unsigned short*)(ws + 30801920);
  // partials 2,3 live in d_out (18874368 B); k_fin fully rewrites y after.
  unsigned short* pO2   = (unsigned short*)d_out;
  unsigned short* pO3   = (unsigned short*)d_out + 4718592;

  k_pre<<<dim3(1376), dim3(256), 0, stream>>>(Wq, Wkv, Wout, x, ngamma, context, clng, clnb,
                                              Wctx, bctx, null_kv, WqT, WkvT, WoutT, xn, kb, vtb);
  k_gemm<0><<<dim3(72, 10), dim3(256), 0, stream>>>(xn, WqT, WkvT, qb, kb, vtb, nullptr);
  k_attn<<<dim3(288, 2, 4), dim3(256), 0, stream>>>(qb, kb, vtb, aoutb, xn, pO2, pO3, lpart);
  k_merge<<<dim3(2304), dim3(256), 0, stream>>>(aoutb, xn, pO2, pO3, lpart);
  k_gemm<1><<<dim3(72, 8), dim3(256), 0, stream>>>(aoutb, WoutT, nullptr, nullptr, nullptr, nullptr, proj);
  k_fin<<<dim3(144, 4), dim3(256), 0, stream>>>(proj, olng, x, y);
}